// Round 9
// baseline (296.363 us; speedup 1.0000x reference)
//
#include <hip/hip_runtime.h>
#include <stdint.h>

// B=8, S=1024, H=1024, NH=16, HD=64
typedef __attribute__((ext_vector_type(8))) __bf16 bf16x8;
typedef __attribute__((ext_vector_type(8))) unsigned short ushortx8;
typedef __attribute__((ext_vector_type(4))) unsigned short ushortx4;
typedef __attribute__((ext_vector_type(4))) short short4v;
typedef __attribute__((ext_vector_type(4))) float floatx4;

#define LOG2E 1.4426950408889634f
#define QSCALE 0.18033688011112043f   // 0.125 * log2e

#define ASYNC16(g, l) __builtin_amdgcn_global_load_lds( \
    (__attribute__((address_space(1))) void*)(g),       \
    (__attribute__((address_space(3))) void*)(l), 16, 0, 0)

__device__ __forceinline__ unsigned short f2bf(float f) {
    unsigned int u = __float_as_uint(f);
    u += 0x7fffu + ((u >> 16) & 1u);   // round-to-nearest-even
    return (unsigned short)(u >> 16);
}
__device__ __forceinline__ float bf2f(unsigned short u) {
    return __uint_as_float((unsigned)u << 16);
}

__device__ __forceinline__ floatx4 mfma32(bf16x8 a, bf16x8 b, floatx4 c) {
    return __builtin_amdgcn_mfma_f32_16x16x32_bf16(a, b, c, 0, 0, 0);
}
__device__ __forceinline__ floatx4 mfma16(short4v a, short4v b, floatx4 c) {
    return __builtin_amdgcn_mfma_f32_16x16x16bf16_1k(a, b, c, 0, 0, 0);
}

// ---------------- fp32 -> bf16 converts (hidden + all 4 weights, one launch) --------
__global__ __launch_bounds__(256) void cvt_all(
    const float* __restrict__ hidden,
    const float* __restrict__ Wq, const float* __restrict__ Wk,
    const float* __restrict__ Wv, const float* __restrict__ Wo,
    unsigned short* __restrict__ hid_bf,
    unsigned short* __restrict__ oqkv, unsigned short* __restrict__ oo)
{
    const float* src;
    unsigned short* dst;
    int i;
    if (blockIdx.x < 4096) {
        src = hidden; dst = hid_bf;
        i = blockIdx.x * 256 + threadIdx.x;          // < 1048576
    } else {
        int blk = (blockIdx.x - 4096) >> 9;
        src = (blk == 0) ? Wq : (blk == 1) ? Wk : (blk == 2) ? Wv : Wo;
        dst = (blk == 3) ? oo : oqkv + (size_t)blk * 1048576;
        i = ((blockIdx.x - 4096) & 511) * 256 + threadIdx.x;   // < 131072
    }
    const float4* p = (const float4*)src + (size_t)i * 2;
    float4 a = p[0], b = p[1];
    ushortx8 o;
    o[0] = f2bf(a.x); o[1] = f2bf(a.y); o[2] = f2bf(a.z); o[3] = f2bf(a.w);
    o[4] = f2bf(b.x); o[5] = f2bf(b.y); o[6] = f2bf(b.z); o[7] = f2bf(b.w);
    *((ushortx8*)dst + i) = o;
}

// ---------- 128x128-tile double-buffered K-loop, ONE barrier per K-tile -------------
// (used by gemm_proj; 64 KB LDS -> 2 blocks/CU)
template<bool SWAP>
__device__ __forceinline__ void kloop_dbuf(
    const unsigned short* __restrict__ Ag,   // pre-offset by srow*1024+scol
    const unsigned short* __restrict__ Wg,
    unsigned short As[2][8192], unsigned short Bs[2][8192],
    int wm, int wn, int l16, int quad, int t,
    floatx4 acc[4][4])
{
    const int t8 = t * 8;
#define SAx(bf_, i_, kt_) ASYNC16(Ag + (size_t)(i_) * 32 * 1024 + (kt_) * 64, &As[bf_][(i_) * 2048 + t8])
#define SBx(bf_, i_, kt_) ASYNC16(Wg + (size_t)(i_) * 32 * 1024 + (kt_) * 64, &Bs[bf_][(i_) * 2048 + t8])
#pragma unroll
    for (int i = 0; i < 4; i++) { SAx(0, i, 0); SBx(0, i, 0); }
    __syncthreads();

#pragma unroll 1
    for (int kt = 0; kt < 16; ++kt) {
        const int cur = kt & 1, nb = cur ^ 1;
        if (kt < 15) {
#pragma unroll
            for (int i = 0; i < 4; i++) { SAx(nb, i, kt + 1); SBx(nb, i, kt + 1); }
        }
#pragma unroll
        for (int s = 0; s < 2; s++) {
            int pb = ((s * 4 + quad) ^ (l16 & 7)) * 8;
            bf16x8 af[4], bfr[4];
#pragma unroll
            for (int mt = 0; mt < 4; mt++)
                af[mt] = *(const bf16x8*)(&As[cur][(wm + mt * 16 + l16) * 64 + pb]);
#pragma unroll
            for (int nt = 0; nt < 4; nt++)
                bfr[nt] = *(const bf16x8*)(&Bs[cur][(wn + nt * 16 + l16) * 64 + pb]);
            if (SWAP) {
#pragma unroll
                for (int ft = 0; ft < 4; ft++)
#pragma unroll
                    for (int st = 0; st < 4; st++)
                        acc[ft][st] = mfma32(bfr[ft], af[st], acc[ft][st]);
            } else {
#pragma unroll
                for (int mt = 0; mt < 4; mt++)
#pragma unroll
                    for (int nt = 0; nt < 4; nt++)
                        acc[mt][nt] = mfma32(af[mt], bfr[nt], acc[mt][nt]);
            }
        }
        __syncthreads();
    }
#undef SAx
#undef SBx
}

// ---------------- merged QKV GEMM: 128x192 tile, dbuf, 2 blocks/CU ------------------
// Delivery model (r0-r8 + m97/m201 cross-check): gemm time = staged_bytes / ~11.6TB/s
// once >=2 blocks/CU provide TLP. 128x192 is the max tile fitting 2 blocks/CU
// (80 KB LDS x2 = full 160 KiB pool; VGPR ~170 < 256): staged 768 -> 656 MB (-17%).
// Grid (64, 16) = 1024 blocks = 2 balanced rounds at 2/CU. Same proven dbuf
// single-barrier loop + swizzle as r8; epilogue per-16-wide-fragment Q/K/V routing.
__global__ __launch_bounds__(256) void gemm_qkv(
    const unsigned short* __restrict__ A,   // [8192][1024] bf16
    const unsigned short* __restrict__ W,   // [Wq;Wk;Wv] [3072][1024]
    const float* __restrict__ bq, const float* __restrict__ bk, const float* __restrict__ bv,
    unsigned short* __restrict__ Qo, unsigned short* __restrict__ Ko,
    unsigned short* __restrict__ Vo)
{
    __shared__ unsigned short As[2][8192];    // [buf][128*64]  16 KB each
    __shared__ unsigned short Bs[2][12288];   // [buf][192*64]  24 KB each
    const int t = threadIdx.x;
    const int wave = t >> 6, lane = t & 63;
    const int quad = lane >> 4, l16 = lane & 15;
    const int wm = (wave >> 1) * 64;    // seq offset (2 wave rows)
    const int wn = (wave & 1) * 96;     // feature offset (2 wave cols of 96)
    const int srow = t >> 3;            // staging row within 32-row unit
    const int scol = ((t & 7) ^ (srow & 7)) * 8;
    const int t8 = t * 8;

    const unsigned short* Ag = A + ((size_t)blockIdx.x * 128 + srow) * 1024 + scol;
    const unsigned short* Wg = W + ((size_t)blockIdx.y * 192 + srow) * 1024 + scol;

#define SA(bf_, i_, kt_) ASYNC16(Ag + (size_t)(i_) * 32 * 1024 + (kt_) * 64, &As[bf_][(i_) * 2048 + t8])
#define SB(bf_, i_, kt_) ASYNC16(Wg + (size_t)(i_) * 32 * 1024 + (kt_) * 64, &Bs[bf_][(i_) * 2048 + t8])

#pragma unroll
    for (int i = 0; i < 4; i++) SA(0, i, 0);
#pragma unroll
    for (int i = 0; i < 6; i++) SB(0, i, 0);
    __syncthreads();

    floatx4 acc[6][4] = {};   // [ft][st]

#pragma unroll 1
    for (int kt = 0; kt < 16; ++kt) {
        const int cur = kt & 1, nb = cur ^ 1;
        if (kt < 15) {
#pragma unroll
            for (int i = 0; i < 4; i++) SA(nb, i, kt + 1);
#pragma unroll
            for (int i = 0; i < 6; i++) SB(nb, i, kt + 1);
        }
#pragma unroll
        for (int s = 0; s < 2; s++) {
            int pb = ((s * 4 + quad) ^ (l16 & 7)) * 8;
            bf16x8 af[4], bfr[6];
#pragma unroll
            for (int mt = 0; mt < 4; mt++)
                af[mt] = *(const bf16x8*)(&As[cur][(wm + mt * 16 + l16) * 64 + pb]);
#pragma unroll
            for (int ft = 0; ft < 6; ft++)
                bfr[ft] = *(const bf16x8*)(&Bs[cur][(wn + ft * 16 + l16) * 64 + pb]);
#pragma unroll
            for (int ft = 0; ft < 6; ft++)
#pragma unroll
                for (int st = 0; st < 4; st++)
                    acc[ft][st] = mfma32(bfr[ft], af[st], acc[ft][st]);
        }
        __syncthreads();
    }
#undef SA
#undef SB

    // Epilogue: per-fragment Q/K/V routing (16-wide fragments; matrix boundaries
    // are multiples of 16).
#pragma unroll
    for (int ft = 0; ft < 6; ++ft) {
        const int featg = blockIdx.y * 192 + wn + ft * 16 + quad * 4;
        const int mat = featg >> 10;           // 0=Q, 1=K, 2=V
        const int fin = featg & 1023;
        if (mat < 2) {
            // Q/K: [b,h,s,d]; lane owns 4 consecutive d -> 8B stores. Q gets QSCALE.
            const float* bp = (mat == 0) ? bq : bk;
            unsigned short* op = (mat == 0) ? Qo : Ko;
            const float sc = (mat == 0) ? QSCALE : 1.0f;
            const float4 b4 = *(const float4*)(bp + fin);
            const int h = fin >> 6, d = fin & 63;
#pragma unroll
            for (int st = 0; st < 4; ++st) {
                const int sg = blockIdx.x * 128 + wm + st * 16 + l16;
                const int b = sg >> 10, s = sg & 1023;
                ushortx4 o4;
                o4[0] = f2bf((acc[ft][st][0] + b4.x) * sc);
                o4[1] = f2bf((acc[ft][st][1] + b4.y) * sc);
                o4[2] = f2bf((acc[ft][st][2] + b4.z) * sc);
                o4[3] = f2bf((acc[ft][st][3] + b4.w) * sc);
                *(ushortx4*)(op + (((size_t)(b * 16 + h) * 1024 + s) * 64 + d)) = o4;
            }
        } else {
            // V: [b,h,d,s'] with per-64-window PV-fragment permutation:
            // s = 64a + st*16 + q*4 + j -> s' = 64a + (st>>1)*32 + q*8 + (st&1)*4 + j
            const float4 b4 = *(const float4*)(bv + fin);
#pragma unroll
            for (int r = 0; r < 4; ++r) {
                const int fr = fin + r;
                const int h = fr >> 6, d = fr & 63;
                const float bias = (r == 0) ? b4.x : (r == 1) ? b4.y : (r == 2) ? b4.z : b4.w;
#pragma unroll
                for (int st = 0; st < 4; ++st) {
                    const int sg = blockIdx.x * 128 + wm + st * 16 + l16;
                    const int b = sg >> 10, s = sg & 1023;
                    const int sp = (s & ~63) + (st >> 1) * 32 + (l16 >> 2) * 8 +
                                   (st & 1) * 4 + (l16 & 3);
                    Vo[((size_t)(b * 16 + h) * 64 + d) * 1024 + sp] = f2bf(acc[ft][st][r] + bias);
                }
            }
        }
    }
}

// ---------------- flash attention: 128-row Q tile, direct-global Q fragments ----------
// grid (128, 8): x = head, y = 128-row q-tile. Softmax VALU diet (r6):
//  - mask folded into QK^T accumulator init; P row-sum via ones-MFMA;
//  - P f32->bf16 via proven shift-truncate (r5's cvt_pk asm NaN'd — don't hand-write).
__global__ __launch_bounds__(256) void attn(
    const unsigned short* __restrict__ Q,   // [b,h,s,d] (scaled by 0.125*log2e)
    const unsigned short* __restrict__ Kg,  // [b,h,s,d]
    const unsigned short* __restrict__ Vt,  // [b,h,d,s'] (permuted)
    const float* __restrict__ mask,         // [B][S]
    unsigned short* __restrict__ ctx)       // [B,S,H] bf16
{
    __shared__ unsigned short Ks[64 * 64];
    __shared__ unsigned short Vs[64 * 64];
    __shared__ float Msall[1024];

    const int t = threadIdx.x;
    const int wave = t >> 6, lane = t & 63, quad = lane >> 4, l16 = lane & 15;
    const int s7 = l16 & 7;
    const int head = blockIdx.x;
    const int b = head >> 4, h = head & 15;
    const int q0 = blockIdx.y * 128;
    const unsigned short* Qh = Q + (size_t)head * 65536;
    const unsigned short* Kh = Kg + (size_t)head * 65536;
    const unsigned short* Vh = Vt + (size_t)head * 65536;

    const int srow = t >> 3;
    const int scol = ((t & 7) ^ (srow & 7)) * 8;

    {   // mask row -> LDS, pre-scaled by log2e
        float4 m4 = *(const float4*)(mask + b * 1024 + t * 4);
        m4.x *= LOG2E; m4.y *= LOG2E; m4.z *= LOG2E; m4.w *= LOG2E;
        *(float4*)(Msall + t * 4) = m4;
    }

    // Q fragments direct from global: qf[qg][s][j] = Q[q0+wave*32+qg*16+l16][s*32+quad*8+j]
    bf16x8 qf[2][2];
#pragma unroll
    for (int qg = 0; qg < 2; qg++) {
        const unsigned short* qp = Qh + (size_t)(q0 + wave * 32 + qg * 16 + l16) * 64 + quad * 8;
        qf[qg][0] = *(const bf16x8*)(qp);
        qf[qg][1] = *(const bf16x8*)(qp + 32);
    }

    const short4v ones = {(short)0x3F80, (short)0x3F80, (short)0x3F80, (short)0x3F80};
    floatx4 sum_acc[2] = {};    // all rows identical = full P row-sum per q-col l16
    floatx4 o_acc[2][4] = {};   // [qg][dt]: O^T rows d = dt*16+quad*4+r, col q = l16

    for (int k0 = 0; k0 < 1024; k0 += 64) {
        __syncthreads();
#pragma unroll
        for (int i = 0; i < 2; i++) {
            ASYNC16(Kh + (size_t)(k0 + i * 32 + srow) * 64 + scol, Ks + i * 2048 + t * 8);
            ASYNC16(Vh + (size_t)(i * 32 + srow) * 1024 + k0 + scol, Vs + i * 2048 + t * 8);
        }
        __syncthreads();

        short4v pf0[4], pf1[4];
#pragma unroll
        for (int nt = 0; nt < 4; nt++) {
            int krow = nt * 16 + l16;
            bf16x8 kf0 = *(const bf16x8*)(Ks + krow * 64 + ((quad ^ s7) * 8));
            bf16x8 kf1 = *(const bf16x8*)(Ks + krow * 64 + (((4 + quad) ^ s7) * 8));
            floatx4 mk = *(const floatx4*)(Msall + k0 + nt * 16 + quad * 4);
            floatx4 z0 = mk;   // mask folded into accumulator init
            z0 = mfma32(kf0, qf[0][0], z0);
            z0 = mfma32(kf1, qf[0][1], z0);
            floatx4 z1 = mk;
            z1 = mfma32(kf0, qf[1][0], z1);
            z1 = mfma32(kf1, qf[1][1], z1);
#pragma unroll
            for (int r = 0; r < 4; r++) {
                pf0[nt][r] = (short)(__float_as_uint(exp2f(z0[r])) >> 16);
                pf1[nt][r] = (short)(__float_as_uint(exp2f(z1[r])) >> 16);
            }
            sum_acc[0] = mfma16(ones, pf0[nt], sum_acc[0]);
            sum_acc[1] = mfma16(ones, pf1[nt], sum_acc[1]);
        }

        // O^T += V^T P^T; Vs permuted so (nt,nt+1) fragments are one b128 read.
#pragma unroll
        for (int dt = 0; dt < 4; dt++) {
            int vrow = dt * 16 + l16;
            ushortx8 v01 = *(const ushortx8*)(Vs + vrow * 64 + ((quad ^ s7) * 8));
            ushortx8 v23 = *(const ushortx8*)(Vs + vrow * 64 + (((4 + quad) ^ s7) * 8));
            short4v vf0 = {(short)v01[0], (short)v01[1], (short)v01[2], (short)v01[3]};
            short4v vf1 = {(short)v01[4], (short)v01[5], (short)v01[6], (short)v01[7]};
            short4v vf2 = {(short)v23[0], (short)v23[1], (short)v23[2], (short)v23[3]};
            short4v vf3 = {(short)v23[4], (short)v23[5], (short)v23[6], (short)v23[7]};
            o_acc[0][dt] = mfma16(vf0, pf0[0], o_acc[0][dt]);
            o_acc[0][dt] = mfma16(vf1, pf0[1], o_acc[0][dt]);
            o_acc[0][dt] = mfma16(vf2, pf0[2], o_acc[0][dt]);
            o_acc[0][dt] = mfma16(vf3, pf0[3], o_acc[0][dt]);
            o_acc[1][dt] = mfma16(vf0, pf1[0], o_acc[1][dt]);
            o_acc[1][dt] = mfma16(vf1, pf1[1], o_acc[1][dt]);
            o_acc[1][dt] = mfma16(vf2, pf1[2], o_acc[1][dt]);
            o_acc[1][dt] = mfma16(vf3, pf1[3], o_acc[1][dt]);
        }
    }

#pragma unroll
    for (int qg = 0; qg < 2; qg++) {
        float inv_l = 1.0f / sum_acc[qg][0];
        int qrow = q0 + wave * 32 + qg * 16 + l16;
#pragma unroll
        for (int dt = 0; dt < 4; dt++) {
            ushortx4 o4;
#pragma unroll
            for (int r = 0; r < 4; r++) o4[r] = f2bf(o_acc[qg][dt][r] * inv_l);
            *(ushortx4*)(ctx + ((size_t)(b * 1024 + qrow)) * 1024 + h * 64 + dt * 16 + quad * 4) = o4;
        }
    }
}

// ---------------- out-proj GEMM + bias + bf16 residual -> x (bf16) ----------------
__global__ __launch_bounds__(256) void gemm_proj(
    const unsigned short* __restrict__ A,   // ctx bf16 [8192][1024]
    const unsigned short* __restrict__ W,   // Wo bf16 [1024][1024]
    const float* __restrict__ bo,
    const unsigned short* __restrict__ resid,  // hid_bf [8192][1024]
    unsigned short* __restrict__ X)         // bf16 [8192][1024]
{
    __shared__ unsigned short As[2][8192];
    __shared__ unsigned short Bs[2][8192];
    const int t = threadIdx.x;
    const int wave = t >> 6, lane = t & 63;
    const int quad = lane >> 4, l16 = lane & 15;
    const int wm = (wave >> 1) * 64, wn = (wave & 1) * 64;
    const int srow = t >> 3;
    const int scol = ((t & 7) ^ (srow & 7)) * 8;

    const unsigned short* Ag = A + ((size_t)blockIdx.x * 128 + srow) * 1024 + scol;
    const unsigned short* Wg = W + ((size_t)blockIdx.y * 128 + srow) * 1024 + scol;

    floatx4 acc[4][4] = {};
    kloop_dbuf<false>(Ag, Wg, As, Bs, wm, wn, l16, quad, t, acc);

#pragma unroll
    for (int nt = 0; nt < 4; nt++) {
        int gn = blockIdx.y * 128 + wn + nt * 16 + l16;
        float bias = bo[gn];
#pragma unroll
        for (int mt = 0; mt < 4; mt++) {
#pragma unroll
            for (int r = 0; r < 4; r++) {
                int gm = blockIdx.x * 128 + wm + mt * 16 + quad * 4 + r;
                size_t off = (size_t)gm * 1024 + gn;
                X[off] = f2bf(acc[mt][nt][r] + bias + bf2f(resid[off]));
            }
        }
    }
}

// ---------------- LayerNorm: one block per token row (bf16 in, fp32 out) ------------
__global__ __launch_bounds__(256) void ln_k(const unsigned short* __restrict__ X,
                                            const float* __restrict__ g,
                                            const float* __restrict__ be,
                                            float* __restrict__ out)
{
    int row = blockIdx.x;
    int t = threadIdx.x;
    const unsigned short* xr = X + (size_t)row * 1024;
    ushortx4 xb = *(const ushortx4*)(xr + t * 4);
    float4 v;
    v.x = bf2f(xb[0]);
    v.y = bf2f(xb[1]);
    v.z = bf2f(xb[2]);
    v.w = bf2f(xb[3]);
    float s = v.x + v.y + v.z + v.w;
    float ss = v.x * v.x + v.y * v.y + v.z * v.z + v.w * v.w;
    for (int off = 1; off < 64; off <<= 1) {
        s += __shfl_xor(s, off);
        ss += __shfl_xor(ss, off);
    }
    __shared__ float red[8];
    int wave = t >> 6, lane = t & 63;
    if (lane == 0) { red[wave] = s; red[4 + wave] = ss; }
    __syncthreads();
    s = red[0] + red[1] + red[2] + red[3];
    ss = red[4] + red[5] + red[6] + red[7];
    float mu = s * (1.f / 1024.f);
    float var = ss * (1.f / 1024.f) - mu * mu;
    float inv = rsqrtf(var + 1e-12f);
    float4 gv = *(const float4*)(g + t * 4);
    float4 bv = *(const float4*)(be + t * 4);
    float4 o;
    o.x = (v.x - mu) * inv * gv.x + bv.x;
    o.y = (v.y - mu) * inv * gv.y + bv.y;
    o.z = (v.z - mu) * inv * gv.z + bv.z;
    o.w = (v.w - mu) * inv * gv.w + bv.w;
    *(float4*)(out + (size_t)row * 1024 + t * 4) = o;
}

extern "C" void kernel_launch(void* const* d_in, const int* in_sizes, int n_in,
                              void* d_out, int out_size, void* d_ws, size_t ws_size,
                              hipStream_t stream)
{
    const float* hidden = (const float*)d_in[0];
    const float* mask   = (const float*)d_in[1];
    const float* Wq = (const float*)d_in[2];
    const float* bq = (const float*)d_in[3];
    const float* Wk = (const float*)d_in[4];
    const float* bk = (const float*)d_in[5];
    const float* Wv = (const float*)d_in[6];
    const float* bv = (const float*)d_in[7];
    const float* Wo = (const float*)d_in[8];
    const float* bo = (const float*)d_in[9];
    const float* gamma = (const float*)d_in[10];
    const float* beta  = (const float*)d_in[11];
    float* out = (float*)d_out;

    char* ws = (char*)d_ws;
    // layout (bytes): hid_bf 16M | wqkv_bf 6M | wo_bf 2M | vt_bf 16M | ctx_bf 16M | q_bf 16M | k_bf 16M
    // x (bf16, 16M) aliases q_bf (dead after attn). total 88M.
    unsigned short* hid_bf  = (unsigned short*)(ws + 0);
    unsigned short* wqkv_bf = (unsigned short*)(ws + 16777216);
    unsigned short* wo_bf   = (unsigned short*)(ws + 23068672);
    unsigned short* vt_bf   = (unsigned short*)(ws + 25165824);
    unsigned short* ctx_bf  = (unsigned short*)(ws + 41943040);
    unsigned short* q_bf    = (unsigned short*)(ws + 58720256);
    unsigned short* k_bf    = (unsigned short*)(ws + 75497472);
    unsigned short* x_bf    = (unsigned short*)(ws + 58720256);

    cvt_all<<<6144, 256, 0, stream>>>(hidden, Wq, Wk, Wv, Wo, hid_bf, wqkv_bf, wo_bf);

    gemm_qkv<<<dim3(64, 16), 256, 0, stream>>>(hid_bf, wqkv_bf, bq, bk, bv, q_bf, k_bf, vt_bf);
    attn<<<dim3(128, 8), 256, 0, stream>>>(q_bf, k_bf, vt_bf, mask, ctx_bf);
    gemm_proj<<<dim3(64, 8), 256, 0, stream>>>(ctx_bf, wo_bf, bo, hid_bf, x_bf);
    ln_k<<<8192, 256, 0, stream>>>(x_bf, gamma, beta, out);
}

// Round 10
// 269.770 us; speedup vs baseline: 1.0986x; 1.0986x over previous
//
#include <hip/hip_runtime.h>
#include <stdint.h>

// B=8, S=1024, H=1024, NH=16, HD=64
typedef __attribute__((ext_vector_type(8))) __bf16 bf16x8;
typedef __attribute__((ext_vector_type(8))) unsigned short ushortx8;
typedef __attribute__((ext_vector_type(4))) unsigned short ushortx4;
typedef __attribute__((ext_vector_type(4))) short short4v;
typedef __attribute__((ext_vector_type(4))) float floatx4;

#define LOG2E 1.4426950408889634f
#define QSCALE 0.18033688011112043f   // 0.125 * log2e

#define ASYNC16(g, l) __builtin_amdgcn_global_load_lds( \
    (__attribute__((address_space(1))) void*)(g),       \
    (__attribute__((address_space(3))) void*)(l), 16, 0, 0)

__device__ __forceinline__ unsigned short f2bf(float f) {
    unsigned int u = __float_as_uint(f);
    u += 0x7fffu + ((u >> 16) & 1u);   // round-to-nearest-even
    return (unsigned short)(u >> 16);
}
__device__ __forceinline__ float bf2f(unsigned short u) {
    return __uint_as_float((unsigned)u << 16);
}

__device__ __forceinline__ floatx4 mfma32(bf16x8 a, bf16x8 b, floatx4 c) {
    return __builtin_amdgcn_mfma_f32_16x16x32_bf16(a, b, c, 0, 0, 0);
}
__device__ __forceinline__ floatx4 mfma16(short4v a, short4v b, floatx4 c) {
    return __builtin_amdgcn_mfma_f32_16x16x16bf16_1k(a, b, c, 0, 0, 0);
}

// ---------------- fp32 -> bf16 converts (hidden + all 4 weights, one launch) --------
__global__ __launch_bounds__(256) void cvt_all(
    const float* __restrict__ hidden,
    const float* __restrict__ Wq, const float* __restrict__ Wk,
    const float* __restrict__ Wv, const float* __restrict__ Wo,
    unsigned short* __restrict__ hid_bf,
    unsigned short* __restrict__ oqkv, unsigned short* __restrict__ oo)
{
    const float* src;
    unsigned short* dst;
    int i;
    if (blockIdx.x < 4096) {
        src = hidden; dst = hid_bf;
        i = blockIdx.x * 256 + threadIdx.x;          // < 1048576
    } else {
        int blk = (blockIdx.x - 4096) >> 9;
        src = (blk == 0) ? Wq : (blk == 1) ? Wk : (blk == 2) ? Wv : Wo;
        dst = (blk == 3) ? oo : oqkv + (size_t)blk * 1048576;
        i = ((blockIdx.x - 4096) & 511) * 256 + threadIdx.x;   // < 131072
    }
    const float4* p = (const float4*)src + (size_t)i * 2;
    float4 a = p[0], b = p[1];
    ushortx8 o;
    o[0] = f2bf(a.x); o[1] = f2bf(a.y); o[2] = f2bf(a.z); o[3] = f2bf(a.w);
    o[4] = f2bf(b.x); o[5] = f2bf(b.y); o[6] = f2bf(b.z); o[7] = f2bf(b.w);
    *((ushortx8*)dst + i) = o;
}

// ---------- 128x128-tile double-buffered K-loop, ONE barrier per K-tile -------------
// (used by gemm_proj; 64 KB LDS -> 2 blocks/CU)
template<bool SWAP>
__device__ __forceinline__ void kloop_dbuf(
    const unsigned short* __restrict__ Ag,   // pre-offset by srow*1024+scol
    const unsigned short* __restrict__ Wg,
    unsigned short As[2][8192], unsigned short Bs[2][8192],
    int wm, int wn, int l16, int quad, int t,
    floatx4 acc[4][4])
{
    const int t8 = t * 8;
#define SAx(bf_, i_, kt_) ASYNC16(Ag + (size_t)(i_) * 32 * 1024 + (kt_) * 64, &As[bf_][(i_) * 2048 + t8])
#define SBx(bf_, i_, kt_) ASYNC16(Wg + (size_t)(i_) * 32 * 1024 + (kt_) * 64, &Bs[bf_][(i_) * 2048 + t8])
#pragma unroll
    for (int i = 0; i < 4; i++) { SAx(0, i, 0); SBx(0, i, 0); }
    __syncthreads();

#pragma unroll 1
    for (int kt = 0; kt < 16; ++kt) {
        const int cur = kt & 1, nb = cur ^ 1;
        if (kt < 15) {
#pragma unroll
            for (int i = 0; i < 4; i++) { SAx(nb, i, kt + 1); SBx(nb, i, kt + 1); }
        }
#pragma unroll
        for (int s = 0; s < 2; s++) {
            int pb = ((s * 4 + quad) ^ (l16 & 7)) * 8;
            bf16x8 af[4], bfr[4];
#pragma unroll
            for (int mt = 0; mt < 4; mt++)
                af[mt] = *(const bf16x8*)(&As[cur][(wm + mt * 16 + l16) * 64 + pb]);
#pragma unroll
            for (int nt = 0; nt < 4; nt++)
                bfr[nt] = *(const bf16x8*)(&Bs[cur][(wn + nt * 16 + l16) * 64 + pb]);
            if (SWAP) {
#pragma unroll
                for (int ft = 0; ft < 4; ft++)
#pragma unroll
                    for (int st = 0; st < 4; st++)
                        acc[ft][st] = mfma32(bfr[ft], af[st], acc[ft][st]);
            } else {
#pragma unroll
                for (int mt = 0; mt < 4; mt++)
#pragma unroll
                    for (int nt = 0; nt < 4; nt++)
                        acc[mt][nt] = mfma32(af[mt], bfr[nt], acc[mt][nt]);
            }
        }
        __syncthreads();
    }
#undef SAx
#undef SBx
}

// ---------------- merged QKV GEMM: 128x256 via A-shared N-rep pair, 64 KB LDS -------
// Delivery model (r0-r9): gemm time = staged_bytes / ~11.3 TB/s IF 2 blocks/CU
// (needs LDS <= 64 KB — r9 proved 80 KB drops to 1 blk/CU and 6 TB/s). This kernel
// keeps r8's exact 64 KB envelope but stages A ONCE for TWO 128-wide B reps:
// As[2] = kt-parity dbuf; Bs[0]/Bs[1] = rep0/rep1 of the CURRENT kt.
//   P0(kt): stage Bs[1]<-rep1(kt);            compute rep0 (As[cur], Bs[0]); sync
//   P1(kt): stage Bs[0]<-rep0(kt+1), As[nb];  compute rep1 (As[cur], Bs[1]); sync
// Every stage lands under the following compute+sync; every written buffer was last
// read in the preceding barrier-terminated sub-phase. Staged: 768 -> 576 MB (-25%).
// Grid (64, 12) = 768 blocks = 3 per CU-pair, balanced. y<4 Q, y<8 K, else V.
__global__ __launch_bounds__(256, 2) void gemm_qkv(
    const unsigned short* __restrict__ A,   // [8192][1024] bf16
    const unsigned short* __restrict__ W,   // [Wq;Wk;Wv] [3072][1024]
    const float* __restrict__ bq, const float* __restrict__ bk, const float* __restrict__ bv,
    unsigned short* __restrict__ Qo, unsigned short* __restrict__ Ko,
    unsigned short* __restrict__ Vo)
{
    __shared__ unsigned short As[2][8192];   // [ktbuf][128*64]
    __shared__ unsigned short Bs[2][8192];   // [rep][128*64]
    const int t = threadIdx.x;
    const int wave = t >> 6, lane = t & 63;
    const int quad = lane >> 4, l16 = lane & 15;
    const int wm = (wave >> 1) * 64, wn = (wave & 1) * 64;
    const int srow = t >> 3;
    const int scol = ((t & 7) ^ (srow & 7)) * 8;
    const int t8 = t * 8;

    const unsigned short* Ag = A + ((size_t)blockIdx.x * 128 + srow) * 1024 + scol;
    const unsigned short* Wg = W + ((size_t)blockIdx.y * 256 + srow) * 1024 + scol;

#define SA(bf_, i_, kt_) ASYNC16(Ag + (size_t)(i_) * 32768 + (kt_) * 64, &As[bf_][(i_) * 2048 + t8])
#define SB(rb_, i_, rp_, kt_) ASYNC16(Wg + (size_t)(rp_) * 131072 + (size_t)(i_) * 32768 + (kt_) * 64, \
                                      &Bs[rb_][(i_) * 2048 + t8])

    // prologue: A(0) + rep0(0)
#pragma unroll
    for (int i = 0; i < 4; i++) { SA(0, i, 0); SB(0, i, 0, 0); }
    __syncthreads();

    floatx4 acc[2][4][4] = {};   // [rep][ft][st]

#pragma unroll 1
    for (int kt = 0; kt < 16; ++kt) {
        const int cur = kt & 1, nb = cur ^ 1;

        // ---- P0: stage rep1(kt) -> Bs[1]; compute rep0 from As[cur], Bs[0] ----
#pragma unroll
        for (int i = 0; i < 4; i++) SB(1, i, 1, kt);
#pragma unroll
        for (int s = 0; s < 2; s++) {
            int pb = ((s * 4 + quad) ^ (l16 & 7)) * 8;
            bf16x8 af[4], bfr[4];
#pragma unroll
            for (int mt = 0; mt < 4; mt++)
                af[mt] = *(const bf16x8*)(&As[cur][(wm + mt * 16 + l16) * 64 + pb]);
#pragma unroll
            for (int ft = 0; ft < 4; ft++)
                bfr[ft] = *(const bf16x8*)(&Bs[0][(wn + ft * 16 + l16) * 64 + pb]);
#pragma unroll
            for (int ft = 0; ft < 4; ft++)
#pragma unroll
                for (int st = 0; st < 4; st++)
                    acc[0][ft][st] = mfma32(bfr[ft], af[st], acc[0][ft][st]);
        }
        __syncthreads();

        // ---- P1: stage rep0(kt+1) -> Bs[0], A(kt+1) -> As[nb]; compute rep1 ----
        if (kt < 15) {
#pragma unroll
            for (int i = 0; i < 4; i++) { SB(0, i, 0, kt + 1); SA(nb, i, kt + 1); }
        }
#pragma unroll
        for (int s = 0; s < 2; s++) {
            int pb = ((s * 4 + quad) ^ (l16 & 7)) * 8;
            bf16x8 af[4], bfr[4];
#pragma unroll
            for (int mt = 0; mt < 4; mt++)
                af[mt] = *(const bf16x8*)(&As[cur][(wm + mt * 16 + l16) * 64 + pb]);
#pragma unroll
            for (int ft = 0; ft < 4; ft++)
                bfr[ft] = *(const bf16x8*)(&Bs[1][(wn + ft * 16 + l16) * 64 + pb]);
#pragma unroll
            for (int ft = 0; ft < 4; ft++)
#pragma unroll
                for (int st = 0; st < 4; st++)
                    acc[1][ft][st] = mfma32(bfr[ft], af[st], acc[1][ft][st]);
        }
        __syncthreads();
    }
#undef SA
#undef SB

    // Epilogue: per-fragment Q/K/V routing over 2 reps x 4 ft (16-wide fragments).
#pragma unroll
    for (int rp = 0; rp < 2; ++rp) {
#pragma unroll
    for (int ft = 0; ft < 4; ++ft) {
        const int featg = blockIdx.y * 256 + rp * 128 + wn + ft * 16 + quad * 4;
        const int mat = featg >> 10;           // 0=Q, 1=K, 2=V
        const int fin = featg & 1023;
        if (mat < 2) {
            // Q/K: [b,h,s,d]; lane owns 4 consecutive d -> 8B stores. Q gets QSCALE.
            const float* bp = (mat == 0) ? bq : bk;
            unsigned short* op = (mat == 0) ? Qo : Ko;
            const float sc = (mat == 0) ? QSCALE : 1.0f;
            const float4 b4 = *(const float4*)(bp + fin);
            const int h = fin >> 6, d = fin & 63;
#pragma unroll
            for (int st = 0; st < 4; ++st) {
                const int sg = blockIdx.x * 128 + wm + st * 16 + l16;
                const int b = sg >> 10, s = sg & 1023;
                ushortx4 o4;
                o4[0] = f2bf((acc[rp][ft][st][0] + b4.x) * sc);
                o4[1] = f2bf((acc[rp][ft][st][1] + b4.y) * sc);
                o4[2] = f2bf((acc[rp][ft][st][2] + b4.z) * sc);
                o4[3] = f2bf((acc[rp][ft][st][3] + b4.w) * sc);
                *(ushortx4*)(op + (((size_t)(b * 16 + h) * 1024 + s) * 64 + d)) = o4;
            }
        } else {
            // V: [b,h,d,s'] with per-64-window PV-fragment permutation:
            // s = 64a + st*16 + q*4 + j -> s' = 64a + (st>>1)*32 + q*8 + (st&1)*4 + j
            const float4 b4 = *(const float4*)(bv + fin);
#pragma unroll
            for (int r = 0; r < 4; ++r) {
                const int fr = fin + r;
                const int h = fr >> 6, d = fr & 63;
                const float bias = (r == 0) ? b4.x : (r == 1) ? b4.y : (r == 2) ? b4.z : b4.w;
#pragma unroll
                for (int st = 0; st < 4; ++st) {
                    const int sg = blockIdx.x * 128 + wm + st * 16 + l16;
                    const int b = sg >> 10, s = sg & 1023;
                    const int sp = (s & ~63) + (st >> 1) * 32 + (l16 >> 2) * 8 +
                                   (st & 1) * 4 + (l16 & 3);
                    Vo[((size_t)(b * 16 + h) * 64 + d) * 1024 + sp] = f2bf(acc[rp][ft][st][r] + bias);
                }
            }
        }
    }
    }
}

// ---------------- flash attention: 128-row Q tile, direct-global Q fragments ----------
// grid (128, 8): x = head, y = 128-row q-tile. Softmax VALU diet (r6):
//  - mask folded into QK^T accumulator init; P row-sum via ones-MFMA;
//  - P f32->bf16 via proven shift-truncate (r5's cvt_pk asm NaN'd — don't hand-write).
__global__ __launch_bounds__(256) void attn(
    const unsigned short* __restrict__ Q,   // [b,h,s,d] (scaled by 0.125*log2e)
    const unsigned short* __restrict__ Kg,  // [b,h,s,d]
    const unsigned short* __restrict__ Vt,  // [b,h,d,s'] (permuted)
    const float* __restrict__ mask,         // [B][S]
    unsigned short* __restrict__ ctx)       // [B,S,H] bf16
{
    __shared__ unsigned short Ks[64 * 64];
    __shared__ unsigned short Vs[64 * 64];
    __shared__ float Msall[1024];

    const int t = threadIdx.x;
    const int wave = t >> 6, lane = t & 63, quad = lane >> 4, l16 = lane & 15;
    const int s7 = l16 & 7;
    const int head = blockIdx.x;
    const int b = head >> 4, h = head & 15;
    const int q0 = blockIdx.y * 128;
    const unsigned short* Qh = Q + (size_t)head * 65536;
    const unsigned short* Kh = Kg + (size_t)head * 65536;
    const unsigned short* Vh = Vt + (size_t)head * 65536;

    const int srow = t >> 3;
    const int scol = ((t & 7) ^ (srow & 7)) * 8;

    {   // mask row -> LDS, pre-scaled by log2e
        float4 m4 = *(const float4*)(mask + b * 1024 + t * 4);
        m4.x *= LOG2E; m4.y *= LOG2E; m4.z *= LOG2E; m4.w *= LOG2E;
        *(float4*)(Msall + t * 4) = m4;
    }

    // Q fragments direct from global: qf[qg][s][j] = Q[q0+wave*32+qg*16+l16][s*32+quad*8+j]
    bf16x8 qf[2][2];
#pragma unroll
    for (int qg = 0; qg < 2; qg++) {
        const unsigned short* qp = Qh + (size_t)(q0 + wave * 32 + qg * 16 + l16) * 64 + quad * 8;
        qf[qg][0] = *(const bf16x8*)(qp);
        qf[qg][1] = *(const bf16x8*)(qp + 32);
    }

    const short4v ones = {(short)0x3F80, (short)0x3F80, (short)0x3F80, (short)0x3F80};
    floatx4 sum_acc[2] = {};    // all rows identical = full P row-sum per q-col l16
    floatx4 o_acc[2][4] = {};   // [qg][dt]: O^T rows d = dt*16+quad*4+r, col q = l16

    for (int k0 = 0; k0 < 1024; k0 += 64) {
        __syncthreads();
#pragma unroll
        for (int i = 0; i < 2; i++) {
            ASYNC16(Kh + (size_t)(k0 + i * 32 + srow) * 64 + scol, Ks + i * 2048 + t * 8);
            ASYNC16(Vh + (size_t)(i * 32 + srow) * 1024 + k0 + scol, Vs + i * 2048 + t * 8);
        }
        __syncthreads();

        short4v pf0[4], pf1[4];
#pragma unroll
        for (int nt = 0; nt < 4; nt++) {
            int krow = nt * 16 + l16;
            bf16x8 kf0 = *(const bf16x8*)(Ks + krow * 64 + ((quad ^ s7) * 8));
            bf16x8 kf1 = *(const bf16x8*)(Ks + krow * 64 + (((4 + quad) ^ s7) * 8));
            floatx4 mk = *(const floatx4*)(Msall + k0 + nt * 16 + quad * 4);
            floatx4 z0 = mk;   // mask folded into accumulator init
            z0 = mfma32(kf0, qf[0][0], z0);
            z0 = mfma32(kf1, qf[0][1], z0);
            floatx4 z1 = mk;
            z1 = mfma32(kf0, qf[1][0], z1);
            z1 = mfma32(kf1, qf[1][1], z1);
#pragma unroll
            for (int r = 0; r < 4; r++) {
                pf0[nt][r] = (short)(__float_as_uint(exp2f(z0[r])) >> 16);
                pf1[nt][r] = (short)(__float_as_uint(exp2f(z1[r])) >> 16);
            }
            sum_acc[0] = mfma16(ones, pf0[nt], sum_acc[0]);
            sum_acc[1] = mfma16(ones, pf1[nt], sum_acc[1]);
        }

        // O^T += V^T P^T; Vs permuted so (nt,nt+1) fragments are one b128 read.
#pragma unroll
        for (int dt = 0; dt < 4; dt++) {
            int vrow = dt * 16 + l16;
            ushortx8 v01 = *(const ushortx8*)(Vs + vrow * 64 + ((quad ^ s7) * 8));
            ushortx8 v23 = *(const ushortx8*)(Vs + vrow * 64 + (((4 + quad) ^ s7) * 8));
            short4v vf0 = {(short)v01[0], (short)v01[1], (short)v01[2], (short)v01[3]};
            short4v vf1 = {(short)v01[4], (short)v01[5], (short)v01[6], (short)v01[7]};
            short4v vf2 = {(short)v23[0], (short)v23[1], (short)v23[2], (short)v23[3]};
            short4v vf3 = {(short)v23[4], (short)v23[5], (short)v23[6], (short)v23[7]};
            o_acc[0][dt] = mfma16(vf0, pf0[0], o_acc[0][dt]);
            o_acc[0][dt] = mfma16(vf1, pf0[1], o_acc[0][dt]);
            o_acc[0][dt] = mfma16(vf2, pf0[2], o_acc[0][dt]);
            o_acc[0][dt] = mfma16(vf3, pf0[3], o_acc[0][dt]);
            o_acc[1][dt] = mfma16(vf0, pf1[0], o_acc[1][dt]);
            o_acc[1][dt] = mfma16(vf1, pf1[1], o_acc[1][dt]);
            o_acc[1][dt] = mfma16(vf2, pf1[2], o_acc[1][dt]);
            o_acc[1][dt] = mfma16(vf3, pf1[3], o_acc[1][dt]);
        }
    }

#pragma unroll
    for (int qg = 0; qg < 2; qg++) {
        float inv_l = 1.0f / sum_acc[qg][0];
        int qrow = q0 + wave * 32 + qg * 16 + l16;
#pragma unroll
        for (int dt = 0; dt < 4; dt++) {
            ushortx4 o4;
#pragma unroll
            for (int r = 0; r < 4; r++) o4[r] = f2bf(o_acc[qg][dt][r] * inv_l);
            *(ushortx4*)(ctx + ((size_t)(b * 1024 + qrow)) * 1024 + h * 64 + dt * 16 + quad * 4) = o4;
        }
    }
}

// ---------------- out-proj GEMM + bias + bf16 residual -> x (bf16) ----------------
__global__ __launch_bounds__(256) void gemm_proj(
    const unsigned short* __restrict__ A,   // ctx bf16 [8192][1024]
    const unsigned short* __restrict__ W,   // Wo bf16 [1024][1024]
    const float* __restrict__ bo,
    const unsigned short* __restrict__ resid,  // hid_bf [8192][1024]
    unsigned short* __restrict__ X)         // bf16 [8192][1024]
{
    __shared__ unsigned short As[2][8192];
    __shared__ unsigned short Bs[2][8192];
    const int t = threadIdx.x;
    const int wave = t >> 6, lane = t & 63;
    const int quad = lane >> 4, l16 = lane & 15;
    const int wm = (wave >> 1) * 64, wn = (wave & 1) * 64;
    const int srow = t >> 3;
    const int scol = ((t & 7) ^ (srow & 7)) * 8;

    const unsigned short* Ag = A + ((size_t)blockIdx.x * 128 + srow) * 1024 + scol;
    const unsigned short* Wg = W + ((size_t)blockIdx.y * 128 + srow) * 1024 + scol;

    floatx4 acc[4][4] = {};
    kloop_dbuf<false>(Ag, Wg, As, Bs, wm, wn, l16, quad, t, acc);

#pragma unroll
    for (int nt = 0; nt < 4; nt++) {
        int gn = blockIdx.y * 128 + wn + nt * 16 + l16;
        float bias = bo[gn];
#pragma unroll
        for (int mt = 0; mt < 4; mt++) {
#pragma unroll
            for (int r = 0; r < 4; r++) {
                int gm = blockIdx.x * 128 + wm + mt * 16 + quad * 4 + r;
                size_t off = (size_t)gm * 1024 + gn;
                X[off] = f2bf(acc[mt][nt][r] + bias + bf2f(resid[off]));
            }
        }
    }
}

// ---------------- LayerNorm: one block per token row (bf16 in, fp32 out) ------------
__global__ __launch_bounds__(256) void ln_k(const unsigned short* __restrict__ X,
                                            const float* __restrict__ g,
                                            const float* __restrict__ be,
                                            float* __restrict__ out)
{
    int row = blockIdx.x;
    int t = threadIdx.x;
    const unsigned short* xr = X + (size_t)row * 1024;
    ushortx4 xb = *(const ushortx4*)(xr + t * 4);
    float4 v;
    v.x = bf2f(xb[0]);
    v.y = bf2f(xb[1]);
    v.z = bf2f(xb[2]);
    v.w = bf2f(xb[3]);
    float s = v.x + v.y + v.z + v.w;
    float ss = v.x * v.x + v.y * v.y + v.z * v.z + v.w * v.w;
    for (int off = 1; off < 64; off <<= 1) {
        s += __shfl_xor(s, off);
        ss += __shfl_xor(ss, off);
    }
    __shared__ float red[8];
    int wave = t >> 6, lane = t & 63;
    if (lane == 0) { red[wave] = s; red[4 + wave] = ss; }
    __syncthreads();
    s = red[0] + red[1] + red[2] + red[3];
    ss = red[4] + red[5] + red[6] + red[7];
    float mu = s * (1.f / 1024.f);
    float var = ss * (1.f / 1024.f) - mu * mu;
    float inv = rsqrtf(var + 1e-12f);
    float4 gv = *(const float4*)(g + t * 4);
    float4 bv = *(const float4*)(be + t * 4);
    float4 o;
    o.x = (v.x - mu) * inv * gv.x + bv.x;
    o.y = (v.y - mu) * inv * gv.y + bv.y;
    o.z = (v.z - mu) * inv * gv.z + bv.z;
    o.w = (v.w - mu) * inv * gv.w + bv.w;
    *(float4*)(out + (size_t)row * 1024 + t * 4) = o;
}

extern "C" void kernel_launch(void* const* d_in, const int* in_sizes, int n_in,
                              void* d_out, int out_size, void* d_ws, size_t ws_size,
                              hipStream_t stream)
{
    const float* hidden = (const float*)d_in[0];
    const float* mask   = (const float*)d_in[1];
    const float* Wq = (const float*)d_in[2];
    const float* bq = (const float*)d_in[3];
    const float* Wk = (const float*)d_in[4];
    const float* bk = (const float*)d_in[5];
    const float* Wv = (const float*)d_in[6];
    const float* bv = (const float*)d_in[7];
    const float* Wo = (const float*)d_in[8];
    const float* bo = (const float*)d_in[9];
    const float* gamma = (const float*)d_in[10];
    const float* beta  = (const float*)d_in[11];
    float* out = (float*)d_out;

    char* ws = (char*)d_ws;
    // layout (bytes): hid_bf 16M | wqkv_bf 6M | wo_bf 2M | vt_bf 16M | ctx_bf 16M | q_bf 16M | k_bf 16M
    // x (bf16, 16M) aliases q_bf (dead after attn). total 88M.
    unsigned short* hid_bf  = (unsigned short*)(ws + 0);
    unsigned short* wqkv_bf = (unsigned short*)(ws + 16777216);
    unsigned short* wo_bf   = (unsigned short*)(ws + 23068672);
    unsigned short* vt_bf   = (unsigned short*)(ws + 25165824);
    unsigned short* ctx_bf  = (unsigned short*)(ws + 41943040);
    unsigned short* q_bf    = (unsigned short*)(ws + 58720256);
    unsigned short* k_bf    = (unsigned short*)(ws + 75497472);
    unsigned short* x_bf    = (unsigned short*)(ws + 58720256);

    cvt_all<<<6144, 256, 0, stream>>>(hidden, Wq, Wk, Wv, Wo, hid_bf, wqkv_bf, wo_bf);

    gemm_qkv<<<dim3(64, 12), 256, 0, stream>>>(hid_bf, wqkv_bf, bq, bk, bv, q_bf, k_bf, vt_bf);
    attn<<<dim3(128, 8), 256, 0, stream>>>(q_bf, k_bf, vt_bf, mask, ctx_bf);
    gemm_proj<<<dim3(64, 8), 256, 0, stream>>>(ctx_bf, wo_bf, bo, hid_bf, x_bf);
    ln_k<<<8192, 256, 0, stream>>>(x_bf, gamma, beta, out);
}

// Round 11
// 259.548 us; speedup vs baseline: 1.1418x; 1.0394x over previous
//
#include <hip/hip_runtime.h>
#include <stdint.h>

// B=8, S=1024, H=1024, NH=16, HD=64
typedef __attribute__((ext_vector_type(8))) __bf16 bf16x8;
typedef __attribute__((ext_vector_type(8))) unsigned short ushortx8;
typedef __attribute__((ext_vector_type(4))) unsigned short ushortx4;
typedef __attribute__((ext_vector_type(4))) short short4v;
typedef __attribute__((ext_vector_type(4))) float floatx4;

#define LOG2E 1.4426950408889634f
#define QSCALE 0.18033688011112043f   // 0.125 * log2e

#define ASYNC16(g, l) __builtin_amdgcn_global_load_lds( \
    (__attribute__((address_space(1))) void*)(g),       \
    (__attribute__((address_space(3))) void*)(l), 16, 0, 0)

__device__ __forceinline__ unsigned short f2bf(float f) {
    unsigned int u = __float_as_uint(f);
    u += 0x7fffu + ((u >> 16) & 1u);   // round-to-nearest-even
    return (unsigned short)(u >> 16);
}
__device__ __forceinline__ float bf2f(unsigned short u) {
    return __uint_as_float((unsigned)u << 16);
}

__device__ __forceinline__ floatx4 mfma32(bf16x8 a, bf16x8 b, floatx4 c) {
    return __builtin_amdgcn_mfma_f32_16x16x32_bf16(a, b, c, 0, 0, 0);
}
__device__ __forceinline__ floatx4 mfma16(short4v a, short4v b, floatx4 c) {
    return __builtin_amdgcn_mfma_f32_16x16x16bf16_1k(a, b, c, 0, 0, 0);
}

// ---------------- fp32 -> bf16 converts (hidden + all 4 weights, one launch) --------
__global__ __launch_bounds__(256) void cvt_all(
    const float* __restrict__ hidden,
    const float* __restrict__ Wq, const float* __restrict__ Wk,
    const float* __restrict__ Wv, const float* __restrict__ Wo,
    unsigned short* __restrict__ hid_bf,
    unsigned short* __restrict__ oqkv, unsigned short* __restrict__ oo)
{
    const float* src;
    unsigned short* dst;
    int i;
    if (blockIdx.x < 4096) {
        src = hidden; dst = hid_bf;
        i = blockIdx.x * 256 + threadIdx.x;          // < 1048576
    } else {
        int blk = (blockIdx.x - 4096) >> 9;
        src = (blk == 0) ? Wq : (blk == 1) ? Wk : (blk == 2) ? Wv : Wo;
        dst = (blk == 3) ? oo : oqkv + (size_t)blk * 1048576;
        i = ((blockIdx.x - 4096) & 511) * 256 + threadIdx.x;   // < 131072
    }
    const float4* p = (const float4*)src + (size_t)i * 2;
    float4 a = p[0], b = p[1];
    ushortx8 o;
    o[0] = f2bf(a.x); o[1] = f2bf(a.y); o[2] = f2bf(a.z); o[3] = f2bf(a.w);
    o[4] = f2bf(b.x); o[5] = f2bf(b.y); o[6] = f2bf(b.z); o[7] = f2bf(b.w);
    *((ushortx8*)dst + i) = o;
}

// ---------- 128x128-tile double-buffered K-loop, ONE barrier per K-tile -------------
// (used by gemm_proj; 64 KB LDS -> 2 blocks/CU)
template<bool SWAP>
__device__ __forceinline__ void kloop_dbuf(
    const unsigned short* __restrict__ Ag,   // pre-offset by srow*1024+scol
    const unsigned short* __restrict__ Wg,
    unsigned short As[2][8192], unsigned short Bs[2][8192],
    int wm, int wn, int l16, int quad, int t,
    floatx4 acc[4][4])
{
    const int t8 = t * 8;
#define SAx(bf_, i_, kt_) ASYNC16(Ag + (size_t)(i_) * 32 * 1024 + (kt_) * 64, &As[bf_][(i_) * 2048 + t8])
#define SBx(bf_, i_, kt_) ASYNC16(Wg + (size_t)(i_) * 32 * 1024 + (kt_) * 64, &Bs[bf_][(i_) * 2048 + t8])
#pragma unroll
    for (int i = 0; i < 4; i++) { SAx(0, i, 0); SBx(0, i, 0); }
    __syncthreads();

#pragma unroll 1
    for (int kt = 0; kt < 16; ++kt) {
        const int cur = kt & 1, nb = cur ^ 1;
        if (kt < 15) {
#pragma unroll
            for (int i = 0; i < 4; i++) { SAx(nb, i, kt + 1); SBx(nb, i, kt + 1); }
        }
#pragma unroll
        for (int s = 0; s < 2; s++) {
            int pb = ((s * 4 + quad) ^ (l16 & 7)) * 8;
            bf16x8 af[4], bfr[4];
#pragma unroll
            for (int mt = 0; mt < 4; mt++)
                af[mt] = *(const bf16x8*)(&As[cur][(wm + mt * 16 + l16) * 64 + pb]);
#pragma unroll
            for (int nt = 0; nt < 4; nt++)
                bfr[nt] = *(const bf16x8*)(&Bs[cur][(wn + nt * 16 + l16) * 64 + pb]);
            if (SWAP) {
#pragma unroll
                for (int ft = 0; ft < 4; ft++)
#pragma unroll
                    for (int st = 0; st < 4; st++)
                        acc[ft][st] = mfma32(bfr[ft], af[st], acc[ft][st]);
            } else {
#pragma unroll
                for (int mt = 0; mt < 4; mt++)
#pragma unroll
                    for (int nt = 0; nt < 4; nt++)
                        acc[mt][nt] = mfma32(af[mt], bfr[nt], acc[mt][nt]);
            }
        }
        __syncthreads();
    }
#undef SAx
#undef SBx
}

// ---------------- merged QKV GEMM: 128x384 via A-shared 3 N-reps, 64 KB LDS ---------
// r10 forensics: A-shared reps cut per-tile-eq cost 22.6 -> 19.7 us, but 768-block
// grid (1.5 rounds) made makespan 2*T. This version: THREE 128-wide reps per block
// -> grid (64, 8) = 512 blocks = EXACTLY one round at 2 blocks/CU (64 KB LDS).
// Staged: A 16MB x 8 + B 6MB x 64 = 512 MB (r8: 768).
// Sub-phases per kt (g = 3kt+rp; parity g&1 gives buffer): P0 computes rep0 from
// Bs[cur] & stages rep1->Bs[nb]; P1 computes rep1 from Bs[nb] & stages rep2->Bs[cur];
// P2 computes rep2 from Bs[cur] & stages rep0(kt+1)->Bs[nb] + A(kt+1)->As[nb].
// Every staged buffer was last read in the preceding barrier-terminated sub-phase;
// every read staged >=1 sub-phase earlier (vmcnt0 drain at each __syncthreads).
__global__ __launch_bounds__(256, 2) void gemm_qkv(
    const unsigned short* __restrict__ A,   // [8192][1024] bf16
    const unsigned short* __restrict__ W,   // [Wq;Wk;Wv] [3072][1024]
    const float* __restrict__ bq, const float* __restrict__ bk, const float* __restrict__ bv,
    unsigned short* __restrict__ Qo, unsigned short* __restrict__ Ko,
    unsigned short* __restrict__ Vo)
{
    __shared__ unsigned short As[2][8192];   // [ktbuf][128*64]
    __shared__ unsigned short Bs[2][8192];   // [pingpong][128*64]
    const int t = threadIdx.x;
    const int wave = t >> 6, lane = t & 63;
    const int quad = lane >> 4, l16 = lane & 15;
    const int wm = (wave >> 1) * 64, wn = (wave & 1) * 64;
    const int srow = t >> 3;
    const int scol = ((t & 7) ^ (srow & 7)) * 8;
    const int t8 = t * 8;

    const unsigned short* Ab = A + ((size_t)blockIdx.x * 128 + srow) * 1024 + scol;
    const unsigned short* Wb = W + ((size_t)blockIdx.y * 384 + srow) * 1024 + scol;

#define SA(bf_, i_, kt_) ASYNC16(Ab + (size_t)(i_) * 32768 + (kt_) * 64, &As[bf_][(i_) * 2048 + t8])
#define SB(rb_, i_, rp_, kt_) ASYNC16(Wb + (size_t)(rp_) * 131072 + (size_t)(i_) * 32768 + (kt_) * 64, \
                                      &Bs[rb_][(i_) * 2048 + t8])
#define REPC(RP, BB)                                                                   \
    do {                                                                               \
        _Pragma("unroll")                                                              \
        for (int s = 0; s < 2; s++) {                                                  \
            int pb = ((s * 4 + quad) ^ (l16 & 7)) * 8;                                 \
            bf16x8 af[4], bfr[4];                                                      \
            _Pragma("unroll")                                                          \
            for (int mt = 0; mt < 4; mt++)                                             \
                af[mt] = *(const bf16x8*)(&As[cur][(wm + mt * 16 + l16) * 64 + pb]);   \
            _Pragma("unroll")                                                          \
            for (int ft = 0; ft < 4; ft++)                                             \
                bfr[ft] = *(const bf16x8*)(&Bs[BB][(wn + ft * 16 + l16) * 64 + pb]);   \
            _Pragma("unroll")                                                          \
            for (int ft = 0; ft < 4; ft++)                                             \
                _Pragma("unroll")                                                      \
                for (int st = 0; st < 4; st++)                                         \
                    acc[RP][ft][st] = mfma32(bfr[ft], af[st], acc[RP][ft][st]);        \
        }                                                                              \
    } while (0)

    // prologue: A(0) + rep0(0) -> Bs[0]
#pragma unroll
    for (int i = 0; i < 4; i++) { SA(0, i, 0); SB(0, i, 0, 0); }
    __syncthreads();

    floatx4 acc[3][4][4] = {};   // [rep][ft][st]

#pragma unroll 1
    for (int kt = 0; kt < 16; ++kt) {
        const int cur = kt & 1, nb = cur ^ 1;

        // ---- P0: stage rep1(kt)->Bs[nb]; compute rep0 (As[cur], Bs[cur]) ----
#pragma unroll
        for (int i = 0; i < 4; i++) SB(nb, i, 1, kt);
        REPC(0, cur);
        __syncthreads();

        // ---- P1: stage rep2(kt)->Bs[cur]; compute rep1 (As[cur], Bs[nb]) ----
#pragma unroll
        for (int i = 0; i < 4; i++) SB(cur, i, 2, kt);
        REPC(1, nb);
        __syncthreads();

        // ---- P2: stage rep0(kt+1)->Bs[nb] + A(kt+1)->As[nb]; compute rep2 ----
        if (kt < 15) {
#pragma unroll
            for (int i = 0; i < 4; i++) { SB(nb, i, 0, kt + 1); SA(nb, i, kt + 1); }
        }
        REPC(2, cur);
        __syncthreads();
    }
#undef REPC
#undef SA
#undef SB

    // Epilogue: per-fragment Q/K/V routing over 3 reps x 4 ft (16-wide fragments;
    // matrix boundaries are multiples of 16).
#pragma unroll
    for (int rp = 0; rp < 3; ++rp) {
#pragma unroll
    for (int ft = 0; ft < 4; ++ft) {
        const int featg = blockIdx.y * 384 + rp * 128 + wn + ft * 16 + quad * 4;
        const int mat = featg >> 10;           // 0=Q, 1=K, 2=V
        const int fin = featg & 1023;
        if (mat < 2) {
            // Q/K: [b,h,s,d]; lane owns 4 consecutive d -> 8B stores. Q gets QSCALE.
            const float* bp = (mat == 0) ? bq : bk;
            unsigned short* op = (mat == 0) ? Qo : Ko;
            const float sc = (mat == 0) ? QSCALE : 1.0f;
            const float4 b4 = *(const float4*)(bp + fin);
            const int h = fin >> 6, d = fin & 63;
#pragma unroll
            for (int st = 0; st < 4; ++st) {
                const int sg = blockIdx.x * 128 + wm + st * 16 + l16;
                const int b = sg >> 10, s = sg & 1023;
                ushortx4 o4;
                o4[0] = f2bf((acc[rp][ft][st][0] + b4.x) * sc);
                o4[1] = f2bf((acc[rp][ft][st][1] + b4.y) * sc);
                o4[2] = f2bf((acc[rp][ft][st][2] + b4.z) * sc);
                o4[3] = f2bf((acc[rp][ft][st][3] + b4.w) * sc);
                *(ushortx4*)(op + (((size_t)(b * 16 + h) * 1024 + s) * 64 + d)) = o4;
            }
        } else {
            // V: [b,h,d,s'] with per-64-window PV-fragment permutation:
            // s = 64a + st*16 + q*4 + j -> s' = 64a + (st>>1)*32 + q*8 + (st&1)*4 + j
            const float4 b4 = *(const float4*)(bv + fin);
#pragma unroll
            for (int r = 0; r < 4; ++r) {
                const int fr = fin + r;
                const int h = fr >> 6, d = fr & 63;
                const float bias = (r == 0) ? b4.x : (r == 1) ? b4.y : (r == 2) ? b4.z : b4.w;
#pragma unroll
                for (int st = 0; st < 4; ++st) {
                    const int sg = blockIdx.x * 128 + wm + st * 16 + l16;
                    const int b = sg >> 10, s = sg & 1023;
                    const int sp = (s & ~63) + (st >> 1) * 32 + (l16 >> 2) * 8 +
                                   (st & 1) * 4 + (l16 & 3);
                    Vo[((size_t)(b * 16 + h) * 64 + d) * 1024 + sp] = f2bf(acc[rp][ft][st][r] + bias);
                }
            }
        }
    }
    }
}

// ---------------- flash attention: 128-row Q tile, direct-global Q fragments ----------
// grid (128, 8): x = head, y = 128-row q-tile. Softmax VALU diet (r6):
//  - mask folded into QK^T accumulator init; P row-sum via ones-MFMA;
//  - P f32->bf16 via proven shift-truncate (r5's cvt_pk asm NaN'd — don't hand-write).
__global__ __launch_bounds__(256) void attn(
    const unsigned short* __restrict__ Q,   // [b,h,s,d] (scaled by 0.125*log2e)
    const unsigned short* __restrict__ Kg,  // [b,h,s,d]
    const unsigned short* __restrict__ Vt,  // [b,h,d,s'] (permuted)
    const float* __restrict__ mask,         // [B][S]
    unsigned short* __restrict__ ctx)       // [B,S,H] bf16
{
    __shared__ unsigned short Ks[64 * 64];
    __shared__ unsigned short Vs[64 * 64];
    __shared__ float Msall[1024];

    const int t = threadIdx.x;
    const int wave = t >> 6, lane = t & 63, quad = lane >> 4, l16 = lane & 15;
    const int s7 = l16 & 7;
    const int head = blockIdx.x;
    const int b = head >> 4, h = head & 15;
    const int q0 = blockIdx.y * 128;
    const unsigned short* Qh = Q + (size_t)head * 65536;
    const unsigned short* Kh = Kg + (size_t)head * 65536;
    const unsigned short* Vh = Vt + (size_t)head * 65536;

    const int srow = t >> 3;
    const int scol = ((t & 7) ^ (srow & 7)) * 8;

    {   // mask row -> LDS, pre-scaled by log2e
        float4 m4 = *(const float4*)(mask + b * 1024 + t * 4);
        m4.x *= LOG2E; m4.y *= LOG2E; m4.z *= LOG2E; m4.w *= LOG2E;
        *(float4*)(Msall + t * 4) = m4;
    }

    // Q fragments direct from global: qf[qg][s][j] = Q[q0+wave*32+qg*16+l16][s*32+quad*8+j]
    bf16x8 qf[2][2];
#pragma unroll
    for (int qg = 0; qg < 2; qg++) {
        const unsigned short* qp = Qh + (size_t)(q0 + wave * 32 + qg * 16 + l16) * 64 + quad * 8;
        qf[qg][0] = *(const bf16x8*)(qp);
        qf[qg][1] = *(const bf16x8*)(qp + 32);
    }

    const short4v ones = {(short)0x3F80, (short)0x3F80, (short)0x3F80, (short)0x3F80};
    floatx4 sum_acc[2] = {};    // all rows identical = full P row-sum per q-col l16
    floatx4 o_acc[2][4] = {};   // [qg][dt]: O^T rows d = dt*16+quad*4+r, col q = l16

    for (int k0 = 0; k0 < 1024; k0 += 64) {
        __syncthreads();
#pragma unroll
        for (int i = 0; i < 2; i++) {
            ASYNC16(Kh + (size_t)(k0 + i * 32 + srow) * 64 + scol, Ks + i * 2048 + t * 8);
            ASYNC16(Vh + (size_t)(i * 32 + srow) * 1024 + k0 + scol, Vs + i * 2048 + t * 8);
        }
        __syncthreads();

        short4v pf0[4], pf1[4];
#pragma unroll
        for (int nt = 0; nt < 4; nt++) {
            int krow = nt * 16 + l16;
            bf16x8 kf0 = *(const bf16x8*)(Ks + krow * 64 + ((quad ^ s7) * 8));
            bf16x8 kf1 = *(const bf16x8*)(Ks + krow * 64 + (((4 + quad) ^ s7) * 8));
            floatx4 mk = *(const floatx4*)(Msall + k0 + nt * 16 + quad * 4);
            floatx4 z0 = mk;   // mask folded into accumulator init
            z0 = mfma32(kf0, qf[0][0], z0);
            z0 = mfma32(kf1, qf[0][1], z0);
            floatx4 z1 = mk;
            z1 = mfma32(kf0, qf[1][0], z1);
            z1 = mfma32(kf1, qf[1][1], z1);
#pragma unroll
            for (int r = 0; r < 4; r++) {
                pf0[nt][r] = (short)(__float_as_uint(exp2f(z0[r])) >> 16);
                pf1[nt][r] = (short)(__float_as_uint(exp2f(z1[r])) >> 16);
            }
            sum_acc[0] = mfma16(ones, pf0[nt], sum_acc[0]);
            sum_acc[1] = mfma16(ones, pf1[nt], sum_acc[1]);
        }

        // O^T += V^T P^T; Vs permuted so (nt,nt+1) fragments are one b128 read.
#pragma unroll
        for (int dt = 0; dt < 4; dt++) {
            int vrow = dt * 16 + l16;
            ushortx8 v01 = *(const ushortx8*)(Vs + vrow * 64 + ((quad ^ s7) * 8));
            ushortx8 v23 = *(const ushortx8*)(Vs + vrow * 64 + (((4 + quad) ^ s7) * 8));
            short4v vf0 = {(short)v01[0], (short)v01[1], (short)v01[2], (short)v01[3]};
            short4v vf1 = {(short)v01[4], (short)v01[5], (short)v01[6], (short)v01[7]};
            short4v vf2 = {(short)v23[0], (short)v23[1], (short)v23[2], (short)v23[3]};
            short4v vf3 = {(short)v23[4], (short)v23[5], (short)v23[6], (short)v23[7]};
            o_acc[0][dt] = mfma16(vf0, pf0[0], o_acc[0][dt]);
            o_acc[0][dt] = mfma16(vf1, pf0[1], o_acc[0][dt]);
            o_acc[0][dt] = mfma16(vf2, pf0[2], o_acc[0][dt]);
            o_acc[0][dt] = mfma16(vf3, pf0[3], o_acc[0][dt]);
            o_acc[1][dt] = mfma16(vf0, pf1[0], o_acc[1][dt]);
            o_acc[1][dt] = mfma16(vf1, pf1[1], o_acc[1][dt]);
            o_acc[1][dt] = mfma16(vf2, pf1[2], o_acc[1][dt]);
            o_acc[1][dt] = mfma16(vf3, pf1[3], o_acc[1][dt]);
        }
    }

#pragma unroll
    for (int qg = 0; qg < 2; qg++) {
        float inv_l = 1.0f / sum_acc[qg][0];
        int qrow = q0 + wave * 32 + qg * 16 + l16;
#pragma unroll
        for (int dt = 0; dt < 4; dt++) {
            ushortx4 o4;
#pragma unroll
            for (int r = 0; r < 4; r++) o4[r] = f2bf(o_acc[qg][dt][r] * inv_l);
            *(ushortx4*)(ctx + ((size_t)(b * 1024 + qrow)) * 1024 + h * 64 + dt * 16 + quad * 4) = o4;
        }
    }
}

// ---------------- out-proj GEMM + bias + bf16 residual -> x (bf16) ----------------
__global__ __launch_bounds__(256) void gemm_proj(
    const unsigned short* __restrict__ A,   // ctx bf16 [8192][1024]
    const unsigned short* __restrict__ W,   // Wo bf16 [1024][1024]
    const float* __restrict__ bo,
    const unsigned short* __restrict__ resid,  // hid_bf [8192][1024]
    unsigned short* __restrict__ X)         // bf16 [8192][1024]
{
    __shared__ unsigned short As[2][8192];
    __shared__ unsigned short Bs[2][8192];
    const int t = threadIdx.x;
    const int wave = t >> 6, lane = t & 63;
    const int quad = lane >> 4, l16 = lane & 15;
    const int wm = (wave >> 1) * 64, wn = (wave & 1) * 64;
    const int srow = t >> 3;
    const int scol = ((t & 7) ^ (srow & 7)) * 8;

    const unsigned short* Ag = A + ((size_t)blockIdx.x * 128 + srow) * 1024 + scol;
    const unsigned short* Wg = W + ((size_t)blockIdx.y * 128 + srow) * 1024 + scol;

    floatx4 acc[4][4] = {};
    kloop_dbuf<false>(Ag, Wg, As, Bs, wm, wn, l16, quad, t, acc);

#pragma unroll
    for (int nt = 0; nt < 4; nt++) {
        int gn = blockIdx.y * 128 + wn + nt * 16 + l16;
        float bias = bo[gn];
#pragma unroll
        for (int mt = 0; mt < 4; mt++) {
#pragma unroll
            for (int r = 0; r < 4; r++) {
                int gm = blockIdx.x * 128 + wm + mt * 16 + quad * 4 + r;
                size_t off = (size_t)gm * 1024 + gn;
                X[off] = f2bf(acc[mt][nt][r] + bias + bf2f(resid[off]));
            }
        }
    }
}

// ---------------- LayerNorm: one block per token row (bf16 in, fp32 out) ------------
__global__ __launch_bounds__(256) void ln_k(const unsigned short* __restrict__ X,
                                            const float* __restrict__ g,
                                            const float* __restrict__ be,
                                            float* __restrict__ out)
{
    int row = blockIdx.x;
    int t = threadIdx.x;
    const unsigned short* xr = X + (size_t)row * 1024;
    ushortx4 xb = *(const ushortx4*)(xr + t * 4);
    float4 v;
    v.x = bf2f(xb[0]);
    v.y = bf2f(xb[1]);
    v.z = bf2f(xb[2]);
    v.w = bf2f(xb[3]);
    float s = v.x + v.y + v.z + v.w;
    float ss = v.x * v.x + v.y * v.y + v.z * v.z + v.w * v.w;
    for (int off = 1; off < 64; off <<= 1) {
        s += __shfl_xor(s, off);
        ss += __shfl_xor(ss, off);
    }
    __shared__ float red[8];
    int wave = t >> 6, lane = t & 63;
    if (lane == 0) { red[wave] = s; red[4 + wave] = ss; }
    __syncthreads();
    s = red[0] + red[1] + red[2] + red[3];
    ss = red[4] + red[5] + red[6] + red[7];
    float mu = s * (1.f / 1024.f);
    float var = ss * (1.f / 1024.f) - mu * mu;
    float inv = rsqrtf(var + 1e-12f);
    float4 gv = *(const float4*)(g + t * 4);
    float4 bv = *(const float4*)(be + t * 4);
    float4 o;
    o.x = (v.x - mu) * inv * gv.x + bv.x;
    o.y = (v.y - mu) * inv * gv.y + bv.y;
    o.z = (v.z - mu) * inv * gv.z + bv.z;
    o.w = (v.w - mu) * inv * gv.w + bv.w;
    *(float4*)(out + (size_t)row * 1024 + t * 4) = o;
}

extern "C" void kernel_launch(void* const* d_in, const int* in_sizes, int n_in,
                              void* d_out, int out_size, void* d_ws, size_t ws_size,
                              hipStream_t stream)
{
    const float* hidden = (const float*)d_in[0];
    const float* mask   = (const float*)d_in[1];
    const float* Wq = (const float*)d_in[2];
    const float* bq = (const float*)d_in[3];
    const float* Wk = (const float*)d_in[4];
    const float* bk = (const float*)d_in[5];
    const float* Wv = (const float*)d_in[6];
    const float* bv = (const float*)d_in[7];
    const float* Wo = (const float*)d_in[8];
    const float* bo = (const float*)d_in[9];
    const float* gamma = (const float*)d_in[10];
    const float* beta  = (const float*)d_in[11];
    float* out = (float*)d_out;

    char* ws = (char*)d_ws;
    // layout (bytes): hid_bf 16M | wqkv_bf 6M | wo_bf 2M | vt_bf 16M | ctx_bf 16M | q_bf 16M | k_bf 16M
    // x (bf16, 16M) aliases q_bf (dead after attn). total 88M.
    unsigned short* hid_bf  = (unsigned short*)(ws + 0);
    unsigned short* wqkv_bf = (unsigned short*)(ws + 16777216);
    unsigned short* wo_bf   = (unsigned short*)(ws + 23068672);
    unsigned short* vt_bf   = (unsigned short*)(ws + 25165824);
    unsigned short* ctx_bf  = (unsigned short*)(ws + 41943040);
    unsigned short* q_bf    = (unsigned short*)(ws + 58720256);
    unsigned short* k_bf    = (unsigned short*)(ws + 75497472);
    unsigned short* x_bf    = (unsigned short*)(ws + 58720256);

    cvt_all<<<6144, 256, 0, stream>>>(hidden, Wq, Wk, Wv, Wo, hid_bf, wqkv_bf, wo_bf);

    gemm_qkv<<<dim3(64, 8), 256, 0, stream>>>(hid_bf, wqkv_bf, bq, bk, bv, q_bf, k_bf, vt_bf);
    attn<<<dim3(128, 8), 256, 0, stream>>>(q_bf, k_bf, vt_bf, mask, ctx_bf);
    gemm_proj<<<dim3(64, 8), 256, 0, stream>>>(ctx_bf, wo_bf, bo, hid_bf, x_bf);
    ln_k<<<8192, 256, 0, stream>>>(x_bf, gamma, beta, out);
}

// Round 12
// 253.734 us; speedup vs baseline: 1.1680x; 1.0229x over previous
//
#include <hip/hip_runtime.h>
#include <stdint.h>

// B=8, S=1024, H=1024, NH=16, HD=64
typedef __attribute__((ext_vector_type(8))) __bf16 bf16x8;
typedef __attribute__((ext_vector_type(8))) unsigned short ushortx8;
typedef __attribute__((ext_vector_type(4))) unsigned short ushortx4;
typedef __attribute__((ext_vector_type(4))) short short4v;
typedef __attribute__((ext_vector_type(4))) float floatx4;

#define LOG2E 1.4426950408889634f
#define QSCALE 0.18033688011112043f   // 0.125 * log2e

#define ASYNC16(g, l) __builtin_amdgcn_global_load_lds( \
    (__attribute__((address_space(1))) void*)(g),       \
    (__attribute__((address_space(3))) void*)(l), 16, 0, 0)

__device__ __forceinline__ unsigned short f2bf(float f) {
    unsigned int u = __float_as_uint(f);
    u += 0x7fffu + ((u >> 16) & 1u);   // round-to-nearest-even
    return (unsigned short)(u >> 16);
}
__device__ __forceinline__ float bf2f(unsigned short u) {
    return __uint_as_float((unsigned)u << 16);
}

// raw v_exp_f32 (2^x). libm exp2f without -ffast-math lowers to a guarded
// __ocml sequence (~6-10 VALU insts); the raw instruction is 1. Inputs here are
// bounded softmax logits; sub-2^-126 results flush to 0 = correct underflow.
__device__ __forceinline__ float fast_exp2(float x) {
#if __has_builtin(__builtin_amdgcn_exp2f)
    return __builtin_amdgcn_exp2f(x);
#else
    float r;
    asm("v_exp_f32 %0, %1" : "=v"(r) : "v"(x));
    return r;
#endif
}

__device__ __forceinline__ floatx4 mfma32(bf16x8 a, bf16x8 b, floatx4 c) {
    return __builtin_amdgcn_mfma_f32_16x16x32_bf16(a, b, c, 0, 0, 0);
}
__device__ __forceinline__ floatx4 mfma16(short4v a, short4v b, floatx4 c) {
    return __builtin_amdgcn_mfma_f32_16x16x16bf16_1k(a, b, c, 0, 0, 0);
}

// ---------------- fp32 -> bf16 converts (hidden + all 4 weights, one launch) --------
__global__ __launch_bounds__(256) void cvt_all(
    const float* __restrict__ hidden,
    const float* __restrict__ Wq, const float* __restrict__ Wk,
    const float* __restrict__ Wv, const float* __restrict__ Wo,
    unsigned short* __restrict__ hid_bf,
    unsigned short* __restrict__ oqkv, unsigned short* __restrict__ oo)
{
    const float* src;
    unsigned short* dst;
    int i;
    if (blockIdx.x < 4096) {
        src = hidden; dst = hid_bf;
        i = blockIdx.x * 256 + threadIdx.x;          // < 1048576
    } else {
        int blk = (blockIdx.x - 4096) >> 9;
        src = (blk == 0) ? Wq : (blk == 1) ? Wk : (blk == 2) ? Wv : Wo;
        dst = (blk == 3) ? oo : oqkv + (size_t)blk * 1048576;
        i = ((blockIdx.x - 4096) & 511) * 256 + threadIdx.x;   // < 131072
    }
    const float4* p = (const float4*)src + (size_t)i * 2;
    float4 a = p[0], b = p[1];
    ushortx8 o;
    o[0] = f2bf(a.x); o[1] = f2bf(a.y); o[2] = f2bf(a.z); o[3] = f2bf(a.w);
    o[4] = f2bf(b.x); o[5] = f2bf(b.y); o[6] = f2bf(b.z); o[7] = f2bf(b.w);
    *((ushortx8*)dst + i) = o;
}

// ---------- 128x128-tile double-buffered K-loop, ONE barrier per K-tile -------------
// (used by gemm_proj; 64 KB LDS -> 2 blocks/CU)
template<bool SWAP>
__device__ __forceinline__ void kloop_dbuf(
    const unsigned short* __restrict__ Ag,   // pre-offset by srow*1024+scol
    const unsigned short* __restrict__ Wg,
    unsigned short As[2][8192], unsigned short Bs[2][8192],
    int wm, int wn, int l16, int quad, int t,
    floatx4 acc[4][4])
{
    const int t8 = t * 8;
#define SAx(bf_, i_, kt_) ASYNC16(Ag + (size_t)(i_) * 32 * 1024 + (kt_) * 64, &As[bf_][(i_) * 2048 + t8])
#define SBx(bf_, i_, kt_) ASYNC16(Wg + (size_t)(i_) * 32 * 1024 + (kt_) * 64, &Bs[bf_][(i_) * 2048 + t8])
#pragma unroll
    for (int i = 0; i < 4; i++) { SAx(0, i, 0); SBx(0, i, 0); }
    __syncthreads();

#pragma unroll 1
    for (int kt = 0; kt < 16; ++kt) {
        const int cur = kt & 1, nb = cur ^ 1;
        if (kt < 15) {
#pragma unroll
            for (int i = 0; i < 4; i++) { SAx(nb, i, kt + 1); SBx(nb, i, kt + 1); }
        }
#pragma unroll
        for (int s = 0; s < 2; s++) {
            int pb = ((s * 4 + quad) ^ (l16 & 7)) * 8;
            bf16x8 af[4], bfr[4];
#pragma unroll
            for (int mt = 0; mt < 4; mt++)
                af[mt] = *(const bf16x8*)(&As[cur][(wm + mt * 16 + l16) * 64 + pb]);
#pragma unroll
            for (int nt = 0; nt < 4; nt++)
                bfr[nt] = *(const bf16x8*)(&Bs[cur][(wn + nt * 16 + l16) * 64 + pb]);
            if (SWAP) {
#pragma unroll
                for (int ft = 0; ft < 4; ft++)
#pragma unroll
                    for (int st = 0; st < 4; st++)
                        acc[ft][st] = mfma32(bfr[ft], af[st], acc[ft][st]);
            } else {
#pragma unroll
                for (int mt = 0; mt < 4; mt++)
#pragma unroll
                    for (int nt = 0; nt < 4; nt++)
                        acc[mt][nt] = mfma32(af[mt], bfr[nt], acc[mt][nt]);
            }
        }
        __syncthreads();
    }
#undef SAx
#undef SBx
}

// ---------------- merged QKV GEMM: 128x384 via A-shared 3 N-reps, 64 KB LDS ---------
// grid (64, 8) = 512 blocks = one balanced round at 2 blocks/CU. Staged 512 MB.
__global__ __launch_bounds__(256, 2) void gemm_qkv(
    const unsigned short* __restrict__ A,   // [8192][1024] bf16
    const unsigned short* __restrict__ W,   // [Wq;Wk;Wv] [3072][1024]
    const float* __restrict__ bq, const float* __restrict__ bk, const float* __restrict__ bv,
    unsigned short* __restrict__ Qo, unsigned short* __restrict__ Ko,
    unsigned short* __restrict__ Vo)
{
    __shared__ unsigned short As[2][8192];   // [ktbuf][128*64]
    __shared__ unsigned short Bs[2][8192];   // [pingpong][128*64]
    const int t = threadIdx.x;
    const int wave = t >> 6, lane = t & 63;
    const int quad = lane >> 4, l16 = lane & 15;
    const int wm = (wave >> 1) * 64, wn = (wave & 1) * 64;
    const int srow = t >> 3;
    const int scol = ((t & 7) ^ (srow & 7)) * 8;
    const int t8 = t * 8;

    const unsigned short* Ab = A + ((size_t)blockIdx.x * 128 + srow) * 1024 + scol;
    const unsigned short* Wb = W + ((size_t)blockIdx.y * 384 + srow) * 1024 + scol;

#define SA(bf_, i_, kt_) ASYNC16(Ab + (size_t)(i_) * 32768 + (kt_) * 64, &As[bf_][(i_) * 2048 + t8])
#define SB(rb_, i_, rp_, kt_) ASYNC16(Wb + (size_t)(rp_) * 131072 + (size_t)(i_) * 32768 + (kt_) * 64, \
                                      &Bs[rb_][(i_) * 2048 + t8])
#define REPC(RP, BB)                                                                   \
    do {                                                                               \
        _Pragma("unroll")                                                              \
        for (int s = 0; s < 2; s++) {                                                  \
            int pb = ((s * 4 + quad) ^ (l16 & 7)) * 8;                                 \
            bf16x8 af[4], bfr[4];                                                      \
            _Pragma("unroll")                                                          \
            for (int mt = 0; mt < 4; mt++)                                             \
                af[mt] = *(const bf16x8*)(&As[cur][(wm + mt * 16 + l16) * 64 + pb]);   \
            _Pragma("unroll")                                                          \
            for (int ft = 0; ft < 4; ft++)                                             \
                bfr[ft] = *(const bf16x8*)(&Bs[BB][(wn + ft * 16 + l16) * 64 + pb]);   \
            _Pragma("unroll")                                                          \
            for (int ft = 0; ft < 4; ft++)                                             \
                _Pragma("unroll")                                                      \
                for (int st = 0; st < 4; st++)                                         \
                    acc[RP][ft][st] = mfma32(bfr[ft], af[st], acc[RP][ft][st]);        \
        }                                                                              \
    } while (0)

    // prologue: A(0) + rep0(0) -> Bs[0]
#pragma unroll
    for (int i = 0; i < 4; i++) { SA(0, i, 0); SB(0, i, 0, 0); }
    __syncthreads();

    floatx4 acc[3][4][4] = {};   // [rep][ft][st]

#pragma unroll 1
    for (int kt = 0; kt < 16; ++kt) {
        const int cur = kt & 1, nb = cur ^ 1;

        // ---- P0: stage rep1(kt)->Bs[nb]; compute rep0 (As[cur], Bs[cur]) ----
#pragma unroll
        for (int i = 0; i < 4; i++) SB(nb, i, 1, kt);
        REPC(0, cur);
        __syncthreads();

        // ---- P1: stage rep2(kt)->Bs[cur]; compute rep1 (As[cur], Bs[nb]) ----
#pragma unroll
        for (int i = 0; i < 4; i++) SB(cur, i, 2, kt);
        REPC(1, nb);
        __syncthreads();

        // ---- P2: stage rep0(kt+1)->Bs[nb] + A(kt+1)->As[nb]; compute rep2 ----
        if (kt < 15) {
#pragma unroll
            for (int i = 0; i < 4; i++) { SB(nb, i, 0, kt + 1); SA(nb, i, kt + 1); }
        }
        REPC(2, cur);
        __syncthreads();
    }
#undef REPC
#undef SA
#undef SB

    // Epilogue: per-fragment Q/K/V routing over 3 reps x 4 ft (16-wide fragments;
    // matrix boundaries are multiples of 16).
#pragma unroll
    for (int rp = 0; rp < 3; ++rp) {
#pragma unroll
    for (int ft = 0; ft < 4; ++ft) {
        const int featg = blockIdx.y * 384 + rp * 128 + wn + ft * 16 + quad * 4;
        const int mat = featg >> 10;           // 0=Q, 1=K, 2=V
        const int fin = featg & 1023;
        if (mat < 2) {
            // Q/K: [b,h,s,d]; lane owns 4 consecutive d -> 8B stores. Q gets QSCALE.
            const float* bp = (mat == 0) ? bq : bk;
            unsigned short* op = (mat == 0) ? Qo : Ko;
            const float sc = (mat == 0) ? QSCALE : 1.0f;
            const float4 b4 = *(const float4*)(bp + fin);
            const int h = fin >> 6, d = fin & 63;
#pragma unroll
            for (int st = 0; st < 4; ++st) {
                const int sg = blockIdx.x * 128 + wm + st * 16 + l16;
                const int b = sg >> 10, s = sg & 1023;
                ushortx4 o4;
                o4[0] = f2bf((acc[rp][ft][st][0] + b4.x) * sc);
                o4[1] = f2bf((acc[rp][ft][st][1] + b4.y) * sc);
                o4[2] = f2bf((acc[rp][ft][st][2] + b4.z) * sc);
                o4[3] = f2bf((acc[rp][ft][st][3] + b4.w) * sc);
                *(ushortx4*)(op + (((size_t)(b * 16 + h) * 1024 + s) * 64 + d)) = o4;
            }
        } else {
            // V: [b,h,d,s'] with per-64-window PV-fragment permutation:
            // s = 64a + st*16 + q*4 + j -> s' = 64a + (st>>1)*32 + q*8 + (st&1)*4 + j
            const float4 b4 = *(const float4*)(bv + fin);
#pragma unroll
            for (int r = 0; r < 4; ++r) {
                const int fr = fin + r;
                const int h = fr >> 6, d = fr & 63;
                const float bias = (r == 0) ? b4.x : (r == 1) ? b4.y : (r == 2) ? b4.z : b4.w;
#pragma unroll
                for (int st = 0; st < 4; ++st) {
                    const int sg = blockIdx.x * 128 + wm + st * 16 + l16;
                    const int b = sg >> 10, s = sg & 1023;
                    const int sp = (s & ~63) + (st >> 1) * 32 + (l16 >> 2) * 8 +
                                   (st & 1) * 4 + (l16 & 3);
                    Vo[((size_t)(b * 16 + h) * 64 + d) * 1024 + sp] = f2bf(acc[rp][ft][st][r] + bias);
                }
            }
        }
    }
    }
}

// ---------------- flash attention: 128-row Q tile, direct-global Q fragments ----------
// grid (128, 8): x = head, y = 128-row q-tile. Softmax VALU diet (r6 + r12):
//  - mask folded into QK^T accumulator init; P row-sum via ones-MFMA;
//  - P f32->bf16 via proven shift-truncate;
//  - exp via RAW v_exp_f32 (r12): libm exp2f lowers to a guarded multi-inst
//    __ocml sequence without fast-math — the hidden 5x VALU multiplier behind
//    r4/r6's stubborn 60% VALUBusy.
__global__ __launch_bounds__(256) void attn(
    const unsigned short* __restrict__ Q,   // [b,h,s,d] (scaled by 0.125*log2e)
    const unsigned short* __restrict__ Kg,  // [b,h,s,d]
    const unsigned short* __restrict__ Vt,  // [b,h,d,s'] (permuted)
    const float* __restrict__ mask,         // [B][S]
    unsigned short* __restrict__ ctx)       // [B,S,H] bf16
{
    __shared__ unsigned short Ks[64 * 64];
    __shared__ unsigned short Vs[64 * 64];
    __shared__ float Msall[1024];

    const int t = threadIdx.x;
    const int wave = t >> 6, lane = t & 63, quad = lane >> 4, l16 = lane & 15;
    const int s7 = l16 & 7;
    const int head = blockIdx.x;
    const int b = head >> 4, h = head & 15;
    const int q0 = blockIdx.y * 128;
    const unsigned short* Qh = Q + (size_t)head * 65536;
    const unsigned short* Kh = Kg + (size_t)head * 65536;
    const unsigned short* Vh = Vt + (size_t)head * 65536;

    const int srow = t >> 3;
    const int scol = ((t & 7) ^ (srow & 7)) * 8;

    {   // mask row -> LDS, pre-scaled by log2e
        float4 m4 = *(const float4*)(mask + b * 1024 + t * 4);
        m4.x *= LOG2E; m4.y *= LOG2E; m4.z *= LOG2E; m4.w *= LOG2E;
        *(float4*)(Msall + t * 4) = m4;
    }

    // Q fragments direct from global: qf[qg][s][j] = Q[q0+wave*32+qg*16+l16][s*32+quad*8+j]
    bf16x8 qf[2][2];
#pragma unroll
    for (int qg = 0; qg < 2; qg++) {
        const unsigned short* qp = Qh + (size_t)(q0 + wave * 32 + qg * 16 + l16) * 64 + quad * 8;
        qf[qg][0] = *(const bf16x8*)(qp);
        qf[qg][1] = *(const bf16x8*)(qp + 32);
    }

    const short4v ones = {(short)0x3F80, (short)0x3F80, (short)0x3F80, (short)0x3F80};
    floatx4 sum_acc[2] = {};    // all rows identical = full P row-sum per q-col l16
    floatx4 o_acc[2][4] = {};   // [qg][dt]: O^T rows d = dt*16+quad*4+r, col q = l16

    for (int k0 = 0; k0 < 1024; k0 += 64) {
        __syncthreads();
#pragma unroll
        for (int i = 0; i < 2; i++) {
            ASYNC16(Kh + (size_t)(k0 + i * 32 + srow) * 64 + scol, Ks + i * 2048 + t * 8);
            ASYNC16(Vh + (size_t)(i * 32 + srow) * 1024 + k0 + scol, Vs + i * 2048 + t * 8);
        }
        __syncthreads();

        short4v pf0[4], pf1[4];
#pragma unroll
        for (int nt = 0; nt < 4; nt++) {
            int krow = nt * 16 + l16;
            bf16x8 kf0 = *(const bf16x8*)(Ks + krow * 64 + ((quad ^ s7) * 8));
            bf16x8 kf1 = *(const bf16x8*)(Ks + krow * 64 + (((4 + quad) ^ s7) * 8));
            floatx4 mk = *(const floatx4*)(Msall + k0 + nt * 16 + quad * 4);
            floatx4 z0 = mk;   // mask folded into accumulator init
            z0 = mfma32(kf0, qf[0][0], z0);
            z0 = mfma32(kf1, qf[0][1], z0);
            floatx4 z1 = mk;
            z1 = mfma32(kf0, qf[1][0], z1);
            z1 = mfma32(kf1, qf[1][1], z1);
#pragma unroll
            for (int r = 0; r < 4; r++) {
                pf0[nt][r] = (short)(__float_as_uint(fast_exp2(z0[r])) >> 16);
                pf1[nt][r] = (short)(__float_as_uint(fast_exp2(z1[r])) >> 16);
            }
            sum_acc[0] = mfma16(ones, pf0[nt], sum_acc[0]);
            sum_acc[1] = mfma16(ones, pf1[nt], sum_acc[1]);
        }

        // O^T += V^T P^T; Vs permuted so (nt,nt+1) fragments are one b128 read.
#pragma unroll
        for (int dt = 0; dt < 4; dt++) {
            int vrow = dt * 16 + l16;
            ushortx8 v01 = *(const ushortx8*)(Vs + vrow * 64 + ((quad ^ s7) * 8));
            ushortx8 v23 = *(const ushortx8*)(Vs + vrow * 64 + (((4 + quad) ^ s7) * 8));
            short4v vf0 = {(short)v01[0], (short)v01[1], (short)v01[2], (short)v01[3]};
            short4v vf1 = {(short)v01[4], (short)v01[5], (short)v01[6], (short)v01[7]};
            short4v vf2 = {(short)v23[0], (short)v23[1], (short)v23[2], (short)v23[3]};
            short4v vf3 = {(short)v23[4], (short)v23[5], (short)v23[6], (short)v23[7]};
            o_acc[0][dt] = mfma16(vf0, pf0[0], o_acc[0][dt]);
            o_acc[0][dt] = mfma16(vf1, pf0[1], o_acc[0][dt]);
            o_acc[0][dt] = mfma16(vf2, pf0[2], o_acc[0][dt]);
            o_acc[0][dt] = mfma16(vf3, pf0[3], o_acc[0][dt]);
            o_acc[1][dt] = mfma16(vf0, pf1[0], o_acc[1][dt]);
            o_acc[1][dt] = mfma16(vf1, pf1[1], o_acc[1][dt]);
            o_acc[1][dt] = mfma16(vf2, pf1[2], o_acc[1][dt]);
            o_acc[1][dt] = mfma16(vf3, pf1[3], o_acc[1][dt]);
        }
    }

#pragma unroll
    for (int qg = 0; qg < 2; qg++) {
        float inv_l = 1.0f / sum_acc[qg][0];
        int qrow = q0 + wave * 32 + qg * 16 + l16;
#pragma unroll
        for (int dt = 0; dt < 4; dt++) {
            ushortx4 o4;
#pragma unroll
            for (int r = 0; r < 4; r++) o4[r] = f2bf(o_acc[qg][dt][r] * inv_l);
            *(ushortx4*)(ctx + ((size_t)(b * 1024 + qrow)) * 1024 + h * 64 + dt * 16 + quad * 4) = o4;
        }
    }
}

// ---------------- out-proj GEMM + bias + bf16 residual -> x (bf16) ----------------
__global__ __launch_bounds__(256) void gemm_proj(
    const unsigned short* __restrict__ A,   // ctx bf16 [8192][1024]
    const unsigned short* __restrict__ W,   // Wo bf16 [1024][1024]
    const float* __restrict__ bo,
    const unsigned short* __restrict__ resid,  // hid_bf [8192][1024]
    unsigned short* __restrict__ X)         // bf16 [8192][1024]
{
    __shared__ unsigned short As[2][8192];
    __shared__ unsigned short Bs[2][8192];
    const int t = threadIdx.x;
    const int wave = t >> 6, lane = t & 63;
    const int quad = lane >> 4, l16 = lane & 15;
    const int wm = (wave >> 1) * 64, wn = (wave & 1) * 64;
    const int srow = t >> 3;
    const int scol = ((t & 7) ^ (srow & 7)) * 8;

    const unsigned short* Ag = A + ((size_t)blockIdx.x * 128 + srow) * 1024 + scol;
    const unsigned short* Wg = W + ((size_t)blockIdx.y * 128 + srow) * 1024 + scol;

    floatx4 acc[4][4] = {};
    kloop_dbuf<false>(Ag, Wg, As, Bs, wm, wn, l16, quad, t, acc);

#pragma unroll
    for (int nt = 0; nt < 4; nt++) {
        int gn = blockIdx.y * 128 + wn + nt * 16 + l16;
        float bias = bo[gn];
#pragma unroll
        for (int mt = 0; mt < 4; mt++) {
#pragma unroll
            for (int r = 0; r < 4; r++) {
                int gm = blockIdx.x * 128 + wm + mt * 16 + quad * 4 + r;
                size_t off = (size_t)gm * 1024 + gn;
                X[off] = f2bf(acc[mt][nt][r] + bias + bf2f(resid[off]));
            }
        }
    }
}

// ---------------- LayerNorm: one block per token row (bf16 in, fp32 out) ------------
__global__ __launch_bounds__(256) void ln_k(const unsigned short* __restrict__ X,
                                            const float* __restrict__ g,
                                            const float* __restrict__ be,
                                            float* __restrict__ out)
{
    int row = blockIdx.x;
    int t = threadIdx.x;
    const unsigned short* xr = X + (size_t)row * 1024;
    ushortx4 xb = *(const ushortx4*)(xr + t * 4);
    float4 v;
    v.x = bf2f(xb[0]);
    v.y = bf2f(xb[1]);
    v.z = bf2f(xb[2]);
    v.w = bf2f(xb[3]);
    float s = v.x + v.y + v.z + v.w;
    float ss = v.x * v.x + v.y * v.y + v.z * v.z + v.w * v.w;
    for (int off = 1; off < 64; off <<= 1) {
        s += __shfl_xor(s, off);
        ss += __shfl_xor(ss, off);
    }
    __shared__ float red[8];
    int wave = t >> 6, lane = t & 63;
    if (lane == 0) { red[wave] = s; red[4 + wave] = ss; }
    __syncthreads();
    s = red[0] + red[1] + red[2] + red[3];
    ss = red[4] + red[5] + red[6] + red[7];
    float mu = s * (1.f / 1024.f);
    float var = ss * (1.f / 1024.f) - mu * mu;
    float inv = rsqrtf(var + 1e-12f);
    float4 gv = *(const float4*)(g + t * 4);
    float4 bv = *(const float4*)(be + t * 4);
    float4 o;
    o.x = (v.x - mu) * inv * gv.x + bv.x;
    o.y = (v.y - mu) * inv * gv.y + bv.y;
    o.z = (v.z - mu) * inv * gv.z + bv.z;
    o.w = (v.w - mu) * inv * gv.w + bv.w;
    *(float4*)(out + (size_t)row * 1024 + t * 4) = o;
}

extern "C" void kernel_launch(void* const* d_in, const int* in_sizes, int n_in,
                              void* d_out, int out_size, void* d_ws, size_t ws_size,
                              hipStream_t stream)
{
    const float* hidden = (const float*)d_in[0];
    const float* mask   = (const float*)d_in[1];
    const float* Wq = (const float*)d_in[2];
    const float* bq = (const float*)d_in[3];
    const float* Wk = (const float*)d_in[4];
    const float* bk = (const float*)d_in[5];
    const float* Wv = (const float*)d_in[6];
    const float* bv = (const float*)d_in[7];
    const float* Wo = (const float*)d_in[8];
    const float* bo = (const float*)d_in[9];
    const float* gamma = (const float*)d_in[10];
    const float* beta  = (const float*)d_in[11];
    float* out = (float*)d_out;

    char* ws = (char*)d_ws;
    // layout (bytes): hid_bf 16M | wqkv_bf 6M | wo_bf 2M | vt_bf 16M | ctx_bf 16M | q_bf 16M | k_bf 16M
    // x (bf16, 16M) aliases q_bf (dead after attn). total 88M.
    unsigned short* hid_bf  = (unsigned short*)(ws + 0);
    unsigned short* wqkv_bf = (unsigned short*)(ws + 16777216);
    unsigned short* wo_bf   = (unsigned short*)(ws + 23068672);
    unsigned short* vt_bf   = (unsigned short*)(ws + 25165824);
    unsigned short* ctx_bf  = (unsigned short*)(ws + 41943040);
    unsigned short* q_bf    = (unsigned short*)(ws + 58720256);
    unsigned short* k_bf    = (unsigned short*)(ws + 75497472);
    unsigned short* x_bf    = (unsigned short*)(ws + 58720256);

    cvt_all<<<6144, 256, 0, stream>>>(hidden, Wq, Wk, Wv, Wo, hid_bf, wqkv_bf, wo_bf);

    gemm_qkv<<<dim3(64, 8), 256, 0, stream>>>(hid_bf, wqkv_bf, bq, bk, bv, q_bf, k_bf, vt_bf);
    attn<<<dim3(128, 8), 256, 0, stream>>>(q_bf, k_bf, vt_bf, mask, ctx_bf);
    gemm_proj<<<dim3(64, 8), 256, 0, stream>>>(ctx_bf, wo_bf, bo, hid_bf, x_bf);
    ln_k<<<8192, 256, 0, stream>>>(x_bf, gamma, beta, out);
}

// Round 13
// 244.252 us; speedup vs baseline: 1.2133x; 1.0388x over previous
//
#include <hip/hip_runtime.h>
#include <stdint.h>

// B=8, S=1024, H=1024, NH=16, HD=64
typedef __attribute__((ext_vector_type(8))) __bf16 bf16x8;
typedef __attribute__((ext_vector_type(8))) unsigned short ushortx8;
typedef __attribute__((ext_vector_type(4))) unsigned short ushortx4;
typedef __attribute__((ext_vector_type(4))) short short4v;
typedef __attribute__((ext_vector_type(4))) float floatx4;

#define LOG2E 1.4426950408889634f
#define QSCALE 0.18033688011112043f   // 0.125 * log2e

#define ASYNC16(g, l) __builtin_amdgcn_global_load_lds( \
    (__attribute__((address_space(1))) void*)(g),       \
    (__attribute__((address_space(3))) void*)(l), 16, 0, 0)

__device__ __forceinline__ unsigned short f2bf(float f) {
    unsigned int u = __float_as_uint(f);
    u += 0x7fffu + ((u >> 16) & 1u);   // round-to-nearest-even
    return (unsigned short)(u >> 16);
}
__device__ __forceinline__ float bf2f(unsigned short u) {
    return __uint_as_float((unsigned)u << 16);
}

// raw v_exp_f32 (2^x). libm exp2f without -ffast-math lowers to a guarded
// __ocml sequence (~6-10 VALU insts); the raw instruction is 1. Inputs here are
// bounded softmax logits; sub-2^-126 results flush to 0 = correct underflow.
__device__ __forceinline__ float fast_exp2(float x) {
#if __has_builtin(__builtin_amdgcn_exp2f)
    return __builtin_amdgcn_exp2f(x);
#else
    float r;
    asm("v_exp_f32 %0, %1" : "=v"(r) : "v"(x));
    return r;
#endif
}

__device__ __forceinline__ floatx4 mfma32(bf16x8 a, bf16x8 b, floatx4 c) {
    return __builtin_amdgcn_mfma_f32_16x16x32_bf16(a, b, c, 0, 0, 0);
}
__device__ __forceinline__ floatx4 mfma16(short4v a, short4v b, floatx4 c) {
    return __builtin_amdgcn_mfma_f32_16x16x16bf16_1k(a, b, c, 0, 0, 0);
}

// ---------------- fp32 -> bf16 converts (hidden + all 4 weights, one launch) --------
__global__ __launch_bounds__(256) void cvt_all(
    const float* __restrict__ hidden,
    const float* __restrict__ Wq, const float* __restrict__ Wk,
    const float* __restrict__ Wv, const float* __restrict__ Wo,
    unsigned short* __restrict__ hid_bf,
    unsigned short* __restrict__ oqkv, unsigned short* __restrict__ oo)
{
    const float* src;
    unsigned short* dst;
    int i;
    if (blockIdx.x < 4096) {
        src = hidden; dst = hid_bf;
        i = blockIdx.x * 256 + threadIdx.x;          // < 1048576
    } else {
        int blk = (blockIdx.x - 4096) >> 9;
        src = (blk == 0) ? Wq : (blk == 1) ? Wk : (blk == 2) ? Wv : Wo;
        dst = (blk == 3) ? oo : oqkv + (size_t)blk * 1048576;
        i = ((blockIdx.x - 4096) & 511) * 256 + threadIdx.x;   // < 131072
    }
    const float4* p = (const float4*)src + (size_t)i * 2;
    float4 a = p[0], b = p[1];
    ushortx8 o;
    o[0] = f2bf(a.x); o[1] = f2bf(a.y); o[2] = f2bf(a.z); o[3] = f2bf(a.w);
    o[4] = f2bf(b.x); o[5] = f2bf(b.y); o[6] = f2bf(b.z); o[7] = f2bf(b.w);
    *((ushortx8*)dst + i) = o;
}

// ---------- 128x128-tile double-buffered K-loop, ONE barrier per K-tile -------------
// (used by gemm_proj; 64 KB LDS -> 2 blocks/CU)
template<bool SWAP>
__device__ __forceinline__ void kloop_dbuf(
    const unsigned short* __restrict__ Ag,   // pre-offset by srow*1024+scol
    const unsigned short* __restrict__ Wg,
    unsigned short As[2][8192], unsigned short Bs[2][8192],
    int wm, int wn, int l16, int quad, int t,
    floatx4 acc[4][4])
{
    const int t8 = t * 8;
#define SAx(bf_, i_, kt_) ASYNC16(Ag + (size_t)(i_) * 32 * 1024 + (kt_) * 64, &As[bf_][(i_) * 2048 + t8])
#define SBx(bf_, i_, kt_) ASYNC16(Wg + (size_t)(i_) * 32 * 1024 + (kt_) * 64, &Bs[bf_][(i_) * 2048 + t8])
#pragma unroll
    for (int i = 0; i < 4; i++) { SAx(0, i, 0); SBx(0, i, 0); }
    __syncthreads();

#pragma unroll 1
    for (int kt = 0; kt < 16; ++kt) {
        const int cur = kt & 1, nb = cur ^ 1;
        if (kt < 15) {
#pragma unroll
            for (int i = 0; i < 4; i++) { SAx(nb, i, kt + 1); SBx(nb, i, kt + 1); }
        }
#pragma unroll
        for (int s = 0; s < 2; s++) {
            int pb = ((s * 4 + quad) ^ (l16 & 7)) * 8;
            bf16x8 af[4], bfr[4];
#pragma unroll
            for (int mt = 0; mt < 4; mt++)
                af[mt] = *(const bf16x8*)(&As[cur][(wm + mt * 16 + l16) * 64 + pb]);
#pragma unroll
            for (int nt = 0; nt < 4; nt++)
                bfr[nt] = *(const bf16x8*)(&Bs[cur][(wn + nt * 16 + l16) * 64 + pb]);
            if (SWAP) {
#pragma unroll
                for (int ft = 0; ft < 4; ft++)
#pragma unroll
                    for (int st = 0; st < 4; st++)
                        acc[ft][st] = mfma32(bfr[ft], af[st], acc[ft][st]);
            } else {
#pragma unroll
                for (int mt = 0; mt < 4; mt++)
#pragma unroll
                    for (int nt = 0; nt < 4; nt++)
                        acc[mt][nt] = mfma32(af[mt], bfr[nt], acc[mt][nt]);
            }
        }
        __syncthreads();
    }
#undef SAx
#undef SBx
}

// ---------------- merged QKV GEMM: 128x384 via A-shared 3 N-reps, 64 KB LDS ---------
// grid (64, 8) = 512 blocks = one balanced round at 2 blocks/CU. Staged 512 MB.
__global__ __launch_bounds__(256, 2) void gemm_qkv(
    const unsigned short* __restrict__ A,   // [8192][1024] bf16
    const unsigned short* __restrict__ W,   // [Wq;Wk;Wv] [3072][1024]
    const float* __restrict__ bq, const float* __restrict__ bk, const float* __restrict__ bv,
    unsigned short* __restrict__ Qo, unsigned short* __restrict__ Ko,
    unsigned short* __restrict__ Vo)
{
    __shared__ unsigned short As[2][8192];   // [ktbuf][128*64]
    __shared__ unsigned short Bs[2][8192];   // [pingpong][128*64]
    const int t = threadIdx.x;
    const int wave = t >> 6, lane = t & 63;
    const int quad = lane >> 4, l16 = lane & 15;
    const int wm = (wave >> 1) * 64, wn = (wave & 1) * 64;
    const int srow = t >> 3;
    const int scol = ((t & 7) ^ (srow & 7)) * 8;
    const int t8 = t * 8;

    const unsigned short* Ab = A + ((size_t)blockIdx.x * 128 + srow) * 1024 + scol;
    const unsigned short* Wb = W + ((size_t)blockIdx.y * 384 + srow) * 1024 + scol;

#define SA(bf_, i_, kt_) ASYNC16(Ab + (size_t)(i_) * 32768 + (kt_) * 64, &As[bf_][(i_) * 2048 + t8])
#define SB(rb_, i_, rp_, kt_) ASYNC16(Wb + (size_t)(rp_) * 131072 + (size_t)(i_) * 32768 + (kt_) * 64, \
                                      &Bs[rb_][(i_) * 2048 + t8])
#define REPC(RP, BB)                                                                   \
    do {                                                                               \
        _Pragma("unroll")                                                              \
        for (int s = 0; s < 2; s++) {                                                  \
            int pb = ((s * 4 + quad) ^ (l16 & 7)) * 8;                                 \
            bf16x8 af[4], bfr[4];                                                      \
            _Pragma("unroll")                                                          \
            for (int mt = 0; mt < 4; mt++)                                             \
                af[mt] = *(const bf16x8*)(&As[cur][(wm + mt * 16 + l16) * 64 + pb]);   \
            _Pragma("unroll")                                                          \
            for (int ft = 0; ft < 4; ft++)                                             \
                bfr[ft] = *(const bf16x8*)(&Bs[BB][(wn + ft * 16 + l16) * 64 + pb]);   \
            _Pragma("unroll")                                                          \
            for (int ft = 0; ft < 4; ft++)                                             \
                _Pragma("unroll")                                                      \
                for (int st = 0; st < 4; st++)                                         \
                    acc[RP][ft][st] = mfma32(bfr[ft], af[st], acc[RP][ft][st]);        \
        }                                                                              \
    } while (0)

    // prologue: A(0) + rep0(0) -> Bs[0]
#pragma unroll
    for (int i = 0; i < 4; i++) { SA(0, i, 0); SB(0, i, 0, 0); }
    __syncthreads();

    floatx4 acc[3][4][4] = {};   // [rep][ft][st]

#pragma unroll 1
    for (int kt = 0; kt < 16; ++kt) {
        const int cur = kt & 1, nb = cur ^ 1;

        // ---- P0: stage rep1(kt)->Bs[nb]; compute rep0 (As[cur], Bs[cur]) ----
#pragma unroll
        for (int i = 0; i < 4; i++) SB(nb, i, 1, kt);
        REPC(0, cur);
        __syncthreads();

        // ---- P1: stage rep2(kt)->Bs[cur]; compute rep1 (As[cur], Bs[nb]) ----
#pragma unroll
        for (int i = 0; i < 4; i++) SB(cur, i, 2, kt);
        REPC(1, nb);
        __syncthreads();

        // ---- P2: stage rep0(kt+1)->Bs[nb] + A(kt+1)->As[nb]; compute rep2 ----
        if (kt < 15) {
#pragma unroll
            for (int i = 0; i < 4; i++) { SB(nb, i, 0, kt + 1); SA(nb, i, kt + 1); }
        }
        REPC(2, cur);
        __syncthreads();
    }
#undef REPC
#undef SA
#undef SB

    // Epilogue: per-fragment Q/K/V routing over 3 reps x 4 ft (16-wide fragments;
    // matrix boundaries are multiples of 16).
#pragma unroll
    for (int rp = 0; rp < 3; ++rp) {
#pragma unroll
    for (int ft = 0; ft < 4; ++ft) {
        const int featg = blockIdx.y * 384 + rp * 128 + wn + ft * 16 + quad * 4;
        const int mat = featg >> 10;           // 0=Q, 1=K, 2=V
        const int fin = featg & 1023;
        if (mat < 2) {
            // Q/K: [b,h,s,d]; lane owns 4 consecutive d -> 8B stores. Q gets QSCALE.
            const float* bp = (mat == 0) ? bq : bk;
            unsigned short* op = (mat == 0) ? Qo : Ko;
            const float sc = (mat == 0) ? QSCALE : 1.0f;
            const float4 b4 = *(const float4*)(bp + fin);
            const int h = fin >> 6, d = fin & 63;
#pragma unroll
            for (int st = 0; st < 4; ++st) {
                const int sg = blockIdx.x * 128 + wm + st * 16 + l16;
                const int b = sg >> 10, s = sg & 1023;
                ushortx4 o4;
                o4[0] = f2bf((acc[rp][ft][st][0] + b4.x) * sc);
                o4[1] = f2bf((acc[rp][ft][st][1] + b4.y) * sc);
                o4[2] = f2bf((acc[rp][ft][st][2] + b4.z) * sc);
                o4[3] = f2bf((acc[rp][ft][st][3] + b4.w) * sc);
                *(ushortx4*)(op + (((size_t)(b * 16 + h) * 1024 + s) * 64 + d)) = o4;
            }
        } else {
            // V: [b,h,d,s'] with per-64-window PV-fragment permutation:
            // s = 64a + st*16 + q*4 + j -> s' = 64a + (st>>1)*32 + q*8 + (st&1)*4 + j
            const float4 b4 = *(const float4*)(bv + fin);
#pragma unroll
            for (int r = 0; r < 4; ++r) {
                const int fr = fin + r;
                const int h = fr >> 6, d = fr & 63;
                const float bias = (r == 0) ? b4.x : (r == 1) ? b4.y : (r == 2) ? b4.z : b4.w;
#pragma unroll
                for (int st = 0; st < 4; ++st) {
                    const int sg = blockIdx.x * 128 + wm + st * 16 + l16;
                    const int b = sg >> 10, s = sg & 1023;
                    const int sp = (s & ~63) + (st >> 1) * 32 + (l16 >> 2) * 8 +
                                   (st & 1) * 4 + (l16 & 3);
                    Vo[((size_t)(b * 16 + h) * 64 + d) * 1024 + sp] = f2bf(acc[rp][ft][st][r] + bias);
                }
            }
        }
    }
    }
}

// ---------------- flash attention: 128-row Q tile, KVBLK=128 (r13) ------------------
// grid (128, 8): x = head, y = 128-row q-tile. r13: two 64-k sub-tiles staged per
// barrier pair (8 iterations instead of 16) — halves barrier/vmcnt-drain events,
// doubles compute per drain. LDS 36.5 KB (still 4 blocks/CU, grid-limited).
// Softmax: mask folded into QK^T C-init; P row-sum via ones-MFMA; P pack via
// shift-truncate; exp via raw v_exp_f32 (r12).
__global__ __launch_bounds__(256) void attn(
    const unsigned short* __restrict__ Q,   // [b,h,s,d] (scaled by 0.125*log2e)
    const unsigned short* __restrict__ Kg,  // [b,h,s,d]
    const unsigned short* __restrict__ Vt,  // [b,h,d,s'] (permuted)
    const float* __restrict__ mask,         // [B][S]
    unsigned short* __restrict__ ctx)       // [B,S,H] bf16
{
    __shared__ unsigned short Ks[2 * 4096];   // [j][64 k-rows x 64 d]
    __shared__ unsigned short Vs[2 * 4096];   // [j][64 d-rows x 64 k]
    __shared__ float Msall[1024];

    const int t = threadIdx.x;
    const int wave = t >> 6, lane = t & 63, quad = lane >> 4, l16 = lane & 15;
    const int s7 = l16 & 7;
    const int head = blockIdx.x;
    const int b = head >> 4, h = head & 15;
    const int q0 = blockIdx.y * 128;
    const unsigned short* Qh = Q + (size_t)head * 65536;
    const unsigned short* Kh = Kg + (size_t)head * 65536;
    const unsigned short* Vh = Vt + (size_t)head * 65536;

    const int srow = t >> 3;
    const int scol = ((t & 7) ^ (srow & 7)) * 8;

    {   // mask row -> LDS, pre-scaled by log2e
        float4 m4 = *(const float4*)(mask + b * 1024 + t * 4);
        m4.x *= LOG2E; m4.y *= LOG2E; m4.z *= LOG2E; m4.w *= LOG2E;
        *(float4*)(Msall + t * 4) = m4;
    }

    // Q fragments direct from global: qf[qg][s][j] = Q[q0+wave*32+qg*16+l16][s*32+quad*8+j]
    bf16x8 qf[2][2];
#pragma unroll
    for (int qg = 0; qg < 2; qg++) {
        const unsigned short* qp = Qh + (size_t)(q0 + wave * 32 + qg * 16 + l16) * 64 + quad * 8;
        qf[qg][0] = *(const bf16x8*)(qp);
        qf[qg][1] = *(const bf16x8*)(qp + 32);
    }

    const short4v ones = {(short)0x3F80, (short)0x3F80, (short)0x3F80, (short)0x3F80};
    floatx4 sum_acc[2] = {};    // all rows identical = full P row-sum per q-col l16
    floatx4 o_acc[2][4] = {};   // [qg][dt]: O^T rows d = dt*16+quad*4+r, col q = l16

    for (int k0 = 0; k0 < 1024; k0 += 128) {
        __syncthreads();
#pragma unroll
        for (int j = 0; j < 2; j++)
#pragma unroll
            for (int i = 0; i < 2; i++) {
                ASYNC16(Kh + (size_t)(k0 + j * 64 + i * 32 + srow) * 64 + scol,
                        Ks + j * 4096 + i * 2048 + t * 8);
                ASYNC16(Vh + (size_t)(i * 32 + srow) * 1024 + k0 + j * 64 + scol,
                        Vs + j * 4096 + i * 2048 + t * 8);
            }
        __syncthreads();

#pragma unroll
        for (int j = 0; j < 2; j++) {
            const unsigned short* Ksj = Ks + j * 4096;
            const unsigned short* Vsj = Vs + j * 4096;
            const int kbase = k0 + j * 64;

            short4v pf0[4], pf1[4];
#pragma unroll
            for (int nt = 0; nt < 4; nt++) {
                int krow = nt * 16 + l16;
                bf16x8 kf0 = *(const bf16x8*)(Ksj + krow * 64 + ((quad ^ s7) * 8));
                bf16x8 kf1 = *(const bf16x8*)(Ksj + krow * 64 + (((4 + quad) ^ s7) * 8));
                floatx4 mk = *(const floatx4*)(Msall + kbase + nt * 16 + quad * 4);
                floatx4 z0 = mk;   // mask folded into accumulator init
                z0 = mfma32(kf0, qf[0][0], z0);
                z0 = mfma32(kf1, qf[0][1], z0);
                floatx4 z1 = mk;
                z1 = mfma32(kf0, qf[1][0], z1);
                z1 = mfma32(kf1, qf[1][1], z1);
#pragma unroll
                for (int r = 0; r < 4; r++) {
                    pf0[nt][r] = (short)(__float_as_uint(fast_exp2(z0[r])) >> 16);
                    pf1[nt][r] = (short)(__float_as_uint(fast_exp2(z1[r])) >> 16);
                }
                sum_acc[0] = mfma16(ones, pf0[nt], sum_acc[0]);
                sum_acc[1] = mfma16(ones, pf1[nt], sum_acc[1]);
            }

            // O^T += V^T P^T; Vs permuted so (nt,nt+1) fragments are one b128 read.
#pragma unroll
            for (int dt = 0; dt < 4; dt++) {
                int vrow = dt * 16 + l16;
                ushortx8 v01 = *(const ushortx8*)(Vsj + vrow * 64 + ((quad ^ s7) * 8));
                ushortx8 v23 = *(const ushortx8*)(Vsj + vrow * 64 + (((4 + quad) ^ s7) * 8));
                short4v vf0 = {(short)v01[0], (short)v01[1], (short)v01[2], (short)v01[3]};
                short4v vf1 = {(short)v01[4], (short)v01[5], (short)v01[6], (short)v01[7]};
                short4v vf2 = {(short)v23[0], (short)v23[1], (short)v23[2], (short)v23[3]};
                short4v vf3 = {(short)v23[4], (short)v23[5], (short)v23[6], (short)v23[7]};
                o_acc[0][dt] = mfma16(vf0, pf0[0], o_acc[0][dt]);
                o_acc[0][dt] = mfma16(vf1, pf0[1], o_acc[0][dt]);
                o_acc[0][dt] = mfma16(vf2, pf0[2], o_acc[0][dt]);
                o_acc[0][dt] = mfma16(vf3, pf0[3], o_acc[0][dt]);
                o_acc[1][dt] = mfma16(vf0, pf1[0], o_acc[1][dt]);
                o_acc[1][dt] = mfma16(vf1, pf1[1], o_acc[1][dt]);
                o_acc[1][dt] = mfma16(vf2, pf1[2], o_acc[1][dt]);
                o_acc[1][dt] = mfma16(vf3, pf1[3], o_acc[1][dt]);
            }
        }
    }

#pragma unroll
    for (int qg = 0; qg < 2; qg++) {
        float inv_l = 1.0f / sum_acc[qg][0];
        int qrow = q0 + wave * 32 + qg * 16 + l16;
#pragma unroll
        for (int dt = 0; dt < 4; dt++) {
            ushortx4 o4;
#pragma unroll
            for (int r = 0; r < 4; r++) o4[r] = f2bf(o_acc[qg][dt][r] * inv_l);
            *(ushortx4*)(ctx + ((size_t)(b * 1024 + qrow)) * 1024 + h * 64 + dt * 16 + quad * 4) = o4;
        }
    }
}

// ---------------- out-proj GEMM + bias + bf16 residual -> x (bf16) ----------------
__global__ __launch_bounds__(256) void gemm_proj(
    const unsigned short* __restrict__ A,   // ctx bf16 [8192][1024]
    const unsigned short* __restrict__ W,   // Wo bf16 [1024][1024]
    const float* __restrict__ bo,
    const unsigned short* __restrict__ resid,  // hid_bf [8192][1024]
    unsigned short* __restrict__ X)         // bf16 [8192][1024]
{
    __shared__ unsigned short As[2][8192];
    __shared__ unsigned short Bs[2][8192];
    const int t = threadIdx.x;
    const int wave = t >> 6, lane = t & 63;
    const int quad = lane >> 4, l16 = lane & 15;
    const int wm = (wave >> 1) * 64, wn = (wave & 1) * 64;
    const int srow = t >> 3;
    const int scol = ((t & 7) ^ (srow & 7)) * 8;

    const unsigned short* Ag = A + ((size_t)blockIdx.x * 128 + srow) * 1024 + scol;
    const unsigned short* Wg = W + ((size_t)blockIdx.y * 128 + srow) * 1024 + scol;

    floatx4 acc[4][4] = {};
    kloop_dbuf<false>(Ag, Wg, As, Bs, wm, wn, l16, quad, t, acc);

#pragma unroll
    for (int nt = 0; nt < 4; nt++) {
        int gn = blockIdx.y * 128 + wn + nt * 16 + l16;
        float bias = bo[gn];
#pragma unroll
        for (int mt = 0; mt < 4; mt++) {
#pragma unroll
            for (int r = 0; r < 4; r++) {
                int gm = blockIdx.x * 128 + wm + mt * 16 + quad * 4 + r;
                size_t off = (size_t)gm * 1024 + gn;
                X[off] = f2bf(acc[mt][nt][r] + bias + bf2f(resid[off]));
            }
        }
    }
}

// ---------------- LayerNorm: one block per token row (bf16 in, fp32 out) ------------
__global__ __launch_bounds__(256) void ln_k(const unsigned short* __restrict__ X,
                                            const float* __restrict__ g,
                                            const float* __restrict__ be,
                                            float* __restrict__ out)
{
    int row = blockIdx.x;
    int t = threadIdx.x;
    const unsigned short* xr = X + (size_t)row * 1024;
    ushortx4 xb = *(const ushortx4*)(xr + t * 4);
    float4 v;
    v.x = bf2f(xb[0]);
    v.y = bf2f(xb[1]);
    v.z = bf2f(xb[2]);
    v.w = bf2f(xb[3]);
    float s = v.x + v.y + v.z + v.w;
    float ss = v.x * v.x + v.y * v.y + v.z * v.z + v.w * v.w;
    for (int off = 1; off < 64; off <<= 1) {
        s += __shfl_xor(s, off);
        ss += __shfl_xor(ss, off);
    }
    __shared__ float red[8];
    int wave = t >> 6, lane = t & 63;
    if (lane == 0) { red[wave] = s; red[4 + wave] = ss; }
    __syncthreads();
    s = red[0] + red[1] + red[2] + red[3];
    ss = red[4] + red[5] + red[6] + red[7];
    float mu = s * (1.f / 1024.f);
    float var = ss * (1.f / 1024.f) - mu * mu;
    float inv = rsqrtf(var + 1e-12f);
    float4 gv = *(const float4*)(g + t * 4);
    float4 bv = *(const float4*)(be + t * 4);
    float4 o;
    o.x = (v.x - mu) * inv * gv.x + bv.x;
    o.y = (v.y - mu) * inv * gv.y + bv.y;
    o.z = (v.z - mu) * inv * gv.z + bv.z;
    o.w = (v.w - mu) * inv * gv.w + bv.w;
    *(float4*)(out + (size_t)row * 1024 + t * 4) = o;
}

extern "C" void kernel_launch(void* const* d_in, const int* in_sizes, int n_in,
                              void* d_out, int out_size, void* d_ws, size_t ws_size,
                              hipStream_t stream)
{
    const float* hidden = (const float*)d_in[0];
    const float* mask   = (const float*)d_in[1];
    const float* Wq = (const float*)d_in[2];
    const float* bq = (const float*)d_in[3];
    const float* Wk = (const float*)d_in[4];
    const float* bk = (const float*)d_in[5];
    const float* Wv = (const float*)d_in[6];
    const float* bv = (const float*)d_in[7];
    const float* Wo = (const float*)d_in[8];
    const float* bo = (const float*)d_in[9];
    const float* gamma = (const float*)d_in[10];
    const float* beta  = (const float*)d_in[11];
    float* out = (float*)d_out;

    char* ws = (char*)d_ws;
    // layout (bytes): hid_bf 16M | wqkv_bf 6M | wo_bf 2M | vt_bf 16M | ctx_bf 16M | q_bf 16M | k_bf 16M
    // x (bf16, 16M) aliases q_bf (dead after attn). total 88M.
    unsigned short* hid_bf  = (unsigned short*)(ws + 0);
    unsigned short* wqkv_bf = (unsigned short*)(ws + 16777216);
    unsigned short* wo_bf   = (unsigned short*)(ws + 23068672);
    unsigned short* vt_bf   = (unsigned short*)(ws + 25165824);
    unsigned short* ctx_bf  = (unsigned short*)(ws + 41943040);
    unsigned short* q_bf    = (unsigned short*)(ws + 58720256);
    unsigned short* k_bf    = (unsigned short*)(ws + 75497472);
    unsigned short* x_bf    = (unsigned short*)(ws + 58720256);

    cvt_all<<<6144, 256, 0, stream>>>(hidden, Wq, Wk, Wv, Wo, hid_bf, wqkv_bf, wo_bf);

    gemm_qkv<<<dim3(64, 8), 256, 0, stream>>>(hid_bf, wqkv_bf, bq, bk, bv, q_bf, k_bf, vt_bf);
    attn<<<dim3(128, 8), 256, 0, stream>>>(q_bf, k_bf, vt_bf, mask, ctx_bf);
    gemm_proj<<<dim3(64, 8), 256, 0, stream>>>(ctx_bf, wo_bf, bo, hid_bf, x_bf);
    ln_k<<<8192, 256, 0, stream>>>(x_bf, gamma, beta, out);
}